// Round 1
// baseline (3212.973 us; speedup 1.0000x reference)
//
#include <hip/hip_runtime.h>
#include <hip/hip_bf16.h>
#include <math.h>

#define N_NODES 20000
#define N_EDGES 160000
#define T_STEPS 8
#define F_INC   256
#define HEADS   4
#define CCH     128
#define KC      512   // HEADS*CCH
#define GHD     128
#define G3      384
#define SLOPE   0.2f

__device__ __forceinline__ float leakyf(float x) { return x > 0.f ? x : SLOPE * x; }

// ---------------------------------------------------------------------------
// Generic tiled fp32 GEMM: C[M,Nt] = A[M,K] @ B (+bias per column)
// bT=0: B stored (K,Nt) row-major.  bT=1: B stored (Nt,K) row-major (C=A@B^T).
// Requires: Nt % 128 == 0, K % 16 == 0, K % 4 == 0 alignment. M guarded.
// ---------------------------------------------------------------------------
#define GBM 128
#define GBN 128
#define GBK 16

__global__ __launch_bounds__(256) void gemm_f32(
    const float* __restrict__ A, const float* __restrict__ B,
    const float* __restrict__ bias, float* __restrict__ C,
    int M, int K, int Nt, int bT)
{
  __shared__ float As[GBK][GBM];
  __shared__ float Bs[GBK][GBN];
  const int tid = threadIdx.x;
  const int bm = blockIdx.y * GBM;
  const int bn = blockIdx.x * GBN;
  const int tr = (tid >> 4) << 3;   // 0..120
  const int tc = (tid & 15) << 3;   // 0..120
  float acc[8][8];
  #pragma unroll
  for (int i = 0; i < 8; ++i)
    #pragma unroll
    for (int j = 0; j < 8; ++j) acc[i][j] = 0.f;

  const int nK = K / GBK;
  for (int kt = 0; kt < nK; ++kt) {
    const int k0 = kt * GBK;
    // A tile: 128 rows x 16 k  (512 float4 slots / 256 threads = 2 each)
    #pragma unroll
    for (int i = 0; i < 2; ++i) {
      int idx = tid + i * 256;
      int r   = idx >> 2;
      int kq  = (idx & 3) << 2;
      float4 v = make_float4(0.f, 0.f, 0.f, 0.f);
      int gr = bm + r;
      if (gr < M) v = *reinterpret_cast<const float4*>(&A[(size_t)gr * K + k0 + kq]);
      As[kq + 0][r] = v.x; As[kq + 1][r] = v.y; As[kq + 2][r] = v.z; As[kq + 3][r] = v.w;
    }
    if (bT) {
      #pragma unroll
      for (int i = 0; i < 2; ++i) {
        int idx = tid + i * 256;
        int c   = idx >> 2;
        int kq  = (idx & 3) << 2;
        float4 v = *reinterpret_cast<const float4*>(&B[(size_t)(bn + c) * K + k0 + kq]);
        Bs[kq + 0][c] = v.x; Bs[kq + 1][c] = v.y; Bs[kq + 2][c] = v.z; Bs[kq + 3][c] = v.w;
      }
    } else {
      #pragma unroll
      for (int i = 0; i < 2; ++i) {
        int idx = tid + i * 256;
        int k   = idx >> 5;
        int cq  = (idx & 31) << 2;
        float4 v = *reinterpret_cast<const float4*>(&B[(size_t)(k0 + k) * Nt + bn + cq]);
        *reinterpret_cast<float4*>(&Bs[k][cq]) = v;
      }
    }
    __syncthreads();
    #pragma unroll
    for (int k = 0; k < GBK; ++k) {
      float a[8], b[8];
      #pragma unroll
      for (int i = 0; i < 8; ++i) a[i] = As[k][tr + i];
      #pragma unroll
      for (int j = 0; j < 8; ++j) b[j] = Bs[k][tc + j];
      #pragma unroll
      for (int i = 0; i < 8; ++i)
        #pragma unroll
        for (int j = 0; j < 8; ++j) acc[i][j] = fmaf(a[i], b[j], acc[i][j]);
    }
    __syncthreads();
  }
  #pragma unroll
  for (int i = 0; i < 8; ++i) {
    int gr = bm + tr + i;
    if (gr < M) {
      #pragma unroll
      for (int j = 0; j < 8; ++j) {
        int gc = bn + tc + j;
        float v = acc[i][j];
        if (bias) v += bias[gc];
        C[(size_t)gr * Nt + gc] = v;
      }
    }
  }
}

// ---------------------------------------------------------------------------
// a_src[n,h] = <xw[n,h,:], att_src[h,:]>,  a_dst likewise. 1 wave / node.
// ---------------------------------------------------------------------------
__global__ __launch_bounds__(256) void a_kernel(
    const float* __restrict__ xw, const float* __restrict__ att_s,
    const float* __restrict__ att_d, float* __restrict__ a_src,
    float* __restrict__ a_dst)
{
  const int wave = threadIdx.x >> 6;
  const int lane = threadIdx.x & 63;
  const int n = blockIdx.x * 4 + wave;
  if (n >= N_NODES) return;
  const int h = lane >> 4;
  const int i = lane & 15;
  float ps = 0.f, pd = 0.f;
  const float* xr = xw + (size_t)n * KC + h * CCH;
  const float* as = att_s + h * CCH;
  const float* ad = att_d + h * CCH;
  #pragma unroll
  for (int j = 0; j < 8; ++j) {
    float x = xr[j * 16 + i];
    ps = fmaf(x, as[j * 16 + i], ps);
    pd = fmaf(x, ad[j * 16 + i], pd);
  }
  #pragma unroll
  for (int m = 8; m >= 1; m >>= 1) {
    ps += __shfl_xor(ps, m);
    pd += __shfl_xor(pd, m);
  }
  if (i == 0) { a_src[n * 4 + h] = ps; a_dst[n * 4 + h] = pd; }
}

// ---------------------------------------------------------------------------
// Edge counting-sort by dst
// ---------------------------------------------------------------------------
__global__ void count_kernel(const int* __restrict__ dst, int* __restrict__ counts) {
  int e = blockIdx.x * blockDim.x + threadIdx.x;
  if (e < N_EDGES) atomicAdd(&counts[dst[e]], 1);
}

__global__ __launch_bounds__(1024) void scan_kernel(
    const int* __restrict__ counts, int* __restrict__ offs)
{
  __shared__ int buf[1024];
  const int tid = threadIdx.x;
  int carry = 0;
  for (int base = 0; base < N_NODES; base += 1024) {
    int i = base + tid;
    int v = (i < N_NODES) ? (counts[i] + 1) : 0;  // +1 = self loop
    buf[tid] = v;
    __syncthreads();
    for (int off = 1; off < 1024; off <<= 1) {
      int add = (tid >= off) ? buf[tid - off] : 0;
      __syncthreads();
      buf[tid] += add;
      __syncthreads();
    }
    int incl = buf[tid];
    if (i < N_NODES) offs[i] = carry + incl - v;  // exclusive
    carry += buf[1023];
    __syncthreads();
  }
  if (tid == 0) offs[N_NODES] = carry;
}

__global__ void scatter_kernel(const int* __restrict__ src, const int* __restrict__ dst,
                               const int* __restrict__ offs, int* __restrict__ cursor,
                               int* __restrict__ ssrc)
{
  int e = blockIdx.x * blockDim.x + threadIdx.x;
  if (e >= N_EDGES + N_NODES) return;
  int s, d;
  if (e < N_EDGES) { s = src[e]; d = dst[e]; }
  else             { s = d = e - N_EDGES; }       // self loops
  int pos = offs[d] + atomicAdd(&cursor[d], 1);
  ssrc[pos] = s;
}

// ---------------------------------------------------------------------------
// Per-dst softmax-weighted aggregation + head-mean + bias + leaky -> y
// One 128-thread block per dst node.
// ---------------------------------------------------------------------------
#define ECH 128
__global__ __launch_bounds__(128) void aggregate_kernel(
    const float* __restrict__ xw, const float* __restrict__ a_src,
    const float* __restrict__ a_dst, const float* __restrict__ b_gat,
    const int* __restrict__ offs, const int* __restrict__ ssrc,
    float* __restrict__ yout)
{
  const int d = blockIdx.x;
  const int tid = threadIdx.x;
  __shared__ int   s_src[ECH];
  __shared__ float s_w[ECH][4];
  __shared__ float s_m[4], s_s[4];
  const int beg = offs[d], end = offs[d + 1];
  if (tid < 4) { s_m[tid] = -1e30f; s_s[tid] = 0.f; }
  __syncthreads();
  const float4 adv = *reinterpret_cast<const float4*>(&a_dst[d * 4]);
  const float ad[4] = {adv.x, adv.y, adv.z, adv.w};

  // phase 1: online segment max / sumexp per head
  for (int base = beg; base < end; base += ECH) {
    int cnt = min(ECH, end - base);
    if (tid < cnt) {
      int s = ssrc[base + tid];
      const float4 asv = *reinterpret_cast<const float4*>(&a_src[s * 4]);
      const float as[4] = {asv.x, asv.y, asv.z, asv.w};
      #pragma unroll
      for (int h = 0; h < 4; ++h) s_w[tid][h] = leakyf(as[h] + ad[h]);
    }
    __syncthreads();
    if (tid < 4) {
      int h = tid;
      float m = s_m[h], sm = s_s[h];
      for (int i2 = 0; i2 < cnt; ++i2) {
        float a = s_w[i2][h];
        if (a > m) { sm *= expf(m - a); m = a; }
        sm += expf(a - m);
      }
      s_m[h] = m; s_s[h] = sm;
    }
    __syncthreads();
  }
  const float m0 = s_m[0], m1 = s_m[1], m2 = s_m[2], m3 = s_m[3];
  const float i0 = 1.f / (s_s[0] + 1e-16f), i1 = 1.f / (s_s[1] + 1e-16f);
  const float i2_ = 1.f / (s_s[2] + 1e-16f), i3 = 1.f / (s_s[3] + 1e-16f);

  // phase 2: weighted accumulate (recompute alpha -> weight)
  float acc0 = 0.f, acc1 = 0.f, acc2 = 0.f, acc3 = 0.f;
  for (int base = beg; base < end; base += ECH) {
    int cnt = min(ECH, end - base);
    __syncthreads();
    if (tid < cnt) {
      int s = ssrc[base + tid];
      s_src[tid] = s;
      const float4 asv = *reinterpret_cast<const float4*>(&a_src[s * 4]);
      s_w[tid][0] = expf(leakyf(asv.x + ad[0]) - m0) * i0;
      s_w[tid][1] = expf(leakyf(asv.y + ad[1]) - m1) * i1;
      s_w[tid][2] = expf(leakyf(asv.z + ad[2]) - m2) * i2_;
      s_w[tid][3] = expf(leakyf(asv.w + ad[3]) - m3) * i3;
    }
    __syncthreads();
    for (int e2 = 0; e2 < cnt; ++e2) {
      const float* xr = xw + (size_t)s_src[e2] * KC;
      float w0 = s_w[e2][0], w1 = s_w[e2][1], w2 = s_w[e2][2], w3 = s_w[e2][3];
      acc0 = fmaf(w0, xr[tid], acc0);
      acc1 = fmaf(w1, xr[128 + tid], acc1);
      acc2 = fmaf(w2, xr[256 + tid], acc2);
      acc3 = fmaf(w3, xr[384 + tid], acc3);
    }
  }
  float v = (acc0 + acc1 + acc2 + acc3) * 0.25f + b_gat[tid];
  yout[(size_t)d * GHD + tid] = leakyf(v);
}

// ---------------------------------------------------------------------------
// GRU elementwise combine
// ---------------------------------------------------------------------------
__global__ void gru_combine(const float* __restrict__ gi, const float* __restrict__ gh,
                            const float* __restrict__ hprev, const float* __restrict__ b_hh,
                            float* __restrict__ hout, int t0)
{
  int idx = blockIdx.x * 256 + threadIdx.x;
  if (idx >= N_NODES * GHD) return;
  int n = idx >> 7, c = idx & 127;
  size_t g = (size_t)n * G3;
  float ir = gi[g + c], iz = gi[g + 128 + c], in_ = gi[g + 256 + c];
  float hr, hz, hn, hp;
  if (t0) { hr = b_hh[c]; hz = b_hh[128 + c]; hn = b_hh[256 + c]; hp = 0.f; }
  else    { hr = gh[g + c]; hz = gh[g + 128 + c]; hn = gh[g + 256 + c]; hp = hprev[idx]; }
  float r = 1.f / (1.f + expf(-(ir + hr)));
  float z = 1.f / (1.f + expf(-(iz + hz)));
  float nn = tanhf(in_ + r * hn);
  hout[idx] = (1.f - z) * nn + z * hp;
}

// ---------------------------------------------------------------------------
// Fused temporal attention + classifier + log_softmax. 1 block / node.
// ---------------------------------------------------------------------------
__global__ __launch_bounds__(128) void attn_kernel(
    const float* __restrict__ ctx, const float* __restrict__ W_in,
    const float* __restrict__ W_out, const float* __restrict__ W_cls,
    const float* __restrict__ b_cls, float* __restrict__ out)
{
  const int n = blockIdx.x;
  const int tid = threadIdx.x;
  __shared__ float c_l[T_STEPS][GHD];
  __shared__ float q_l[GHD];
  __shared__ float comb[2 * GHD];
  __shared__ float sc[T_STEPS];
  __shared__ float wts[T_STEPS];
  __shared__ float lred[4];
  #pragma unroll
  for (int t = 0; t < T_STEPS; ++t)
    c_l[t][tid] = ctx[((size_t)t * N_NODES + n) * GHD + tid];
  __syncthreads();
  // q = last @ W_in^T
  float accq = 0.f;
  const float* wr = W_in + (size_t)tid * GHD;
  #pragma unroll 8
  for (int k = 0; k < GHD; ++k) accq = fmaf(wr[k], c_l[T_STEPS - 1][k], accq);
  q_l[tid] = accq;
  __syncthreads();
  // scores over t: 8 groups of 16 lanes
  {
    const int g = tid >> 4, i = tid & 15;
    float p = 0.f;
    #pragma unroll
    for (int j = 0; j < 8; ++j) p = fmaf(q_l[j * 16 + i], c_l[g][j * 16 + i], p);
    p += __shfl_xor(p, 8);
    p += __shfl_xor(p, 4);
    p += __shfl_xor(p, 2);
    p += __shfl_xor(p, 1);
    if (i == 0) sc[g] = p;
  }
  __syncthreads();
  if (tid == 0) {
    float mx = sc[0];
    #pragma unroll
    for (int t = 1; t < T_STEPS; ++t) mx = fmaxf(mx, sc[t]);
    float s = 0.f, e[T_STEPS];
    #pragma unroll
    for (int t = 0; t < T_STEPS; ++t) { e[t] = expf(sc[t] - mx); s += e[t]; }
    float inv = 1.f / s;
    #pragma unroll
    for (int t = 0; t < T_STEPS; ++t) wts[t] = e[t] * inv;
  }
  __syncthreads();
  float mix = 0.f;
  #pragma unroll
  for (int t = 0; t < T_STEPS; ++t) mix = fmaf(wts[t], c_l[t][tid], mix);
  comb[tid] = mix;
  comb[GHD + tid] = q_l[tid];
  __syncthreads();
  float a2 = 0.f;
  const float* wo = W_out + (size_t)tid * 2 * GHD;
  #pragma unroll 8
  for (int j = 0; j < 2 * GHD; ++j) a2 = fmaf(wo[j], comb[j], a2);
  float o1 = leakyf(tanhf(a2));
  float p0 = o1 * W_cls[tid];
  float p1 = o1 * W_cls[GHD + tid];
  #pragma unroll
  for (int m = 32; m >= 1; m >>= 1) { p0 += __shfl_xor(p0, m); p1 += __shfl_xor(p1, m); }
  if ((tid & 63) == 0) { lred[tid >> 6] = p0; lred[2 + (tid >> 6)] = p1; }
  __syncthreads();
  if (tid == 0) {
    float l0 = lred[0] + lred[1] + b_cls[0];
    float l1 = lred[2] + lred[3] + b_cls[1];
    float mx = fmaxf(l0, l1);
    float lse = mx + logf(expf(l0 - mx) + expf(l1 - mx));
    out[(size_t)n * 2 + 0] = l0 - lse;
    out[(size_t)n * 2 + 1] = l1 - lse;
  }
}

// ---------------------------------------------------------------------------
extern "C" void kernel_launch(void* const* d_in, const int* in_sizes, int n_in,
                              void* d_out, int out_size, void* d_ws, size_t ws_size,
                              hipStream_t stream)
{
  const int*   graph     = (const int*)  d_in[0];
  const float* fts       = (const float*)d_in[1];
  const float* W_gat     = (const float*)d_in[3];
  const float* att_src   = (const float*)d_in[4];
  const float* att_dst   = (const float*)d_in[5];
  const float* b_gat     = (const float*)d_in[6];
  const float* W_ih      = (const float*)d_in[7];
  const float* W_hh      = (const float*)d_in[8];
  const float* b_ih      = (const float*)d_in[9];
  const float* b_hh      = (const float*)d_in[10];
  const float* W_att_in  = (const float*)d_in[11];
  const float* W_att_out = (const float*)d_in[12];
  const float* W_cls     = (const float*)d_in[13];
  const float* b_cls     = (const float*)d_in[14];
  float* out = (float*)d_out;

  char* ws = (char*)d_ws;
  size_t off = 0;
  auto alloc = [&](size_t bytes) {
    void* p = ws + off;
    off = (off + bytes + 255) & ~(size_t)255;
    return p;
  };
  float* xw   = (float*)alloc((size_t)N_NODES * KC * 4);          // 41 MB (per-t reuse)
  float* asrc = (float*)alloc((size_t)N_NODES * 4 * 4);
  float* adst = (float*)alloc((size_t)N_NODES * 4 * 4);
  float* yb   = (float*)alloc((size_t)N_NODES * GHD * 4);         // per-t reuse
  float* gi   = (float*)alloc((size_t)N_NODES * G3 * 4);
  float* gh   = (float*)alloc((size_t)N_NODES * G3 * 4);
  float* ctx  = (float*)alloc((size_t)T_STEPS * N_NODES * GHD * 4); // 82 MB
  int* counts = (int*)alloc((size_t)N_NODES * 4);
  int* offs   = (int*)alloc((size_t)(N_NODES + 1) * 4);
  int* cursor = (int*)alloc((size_t)N_NODES * 4);
  int* ssrc   = (int*)alloc((size_t)(N_EDGES + N_NODES) * 4);

  for (int t = 0; t < T_STEPS; ++t) {
    const float* ft  = fts + (size_t)t * N_NODES * F_INC;
    const int* esrc  = graph + (size_t)t * 2 * N_EDGES;
    const int* edst  = esrc + N_EDGES;

    // GAT
    gemm_f32<<<dim3(KC / GBN, (N_NODES + GBM - 1) / GBM), 256, 0, stream>>>(
        ft, W_gat, nullptr, xw, N_NODES, F_INC, KC, 0);
    a_kernel<<<dim3(N_NODES / 4), 256, 0, stream>>>(xw, att_src, att_dst, asrc, adst);
    hipMemsetAsync(counts, 0, (size_t)N_NODES * 4, stream);
    count_kernel<<<dim3((N_EDGES + 255) / 256), 256, 0, stream>>>(edst, counts);
    scan_kernel<<<dim3(1), 1024, 0, stream>>>(counts, offs);
    hipMemsetAsync(cursor, 0, (size_t)N_NODES * 4, stream);
    scatter_kernel<<<dim3((N_EDGES + N_NODES + 255) / 256), 256, 0, stream>>>(
        esrc, edst, offs, cursor, ssrc);
    aggregate_kernel<<<dim3(N_NODES), 128, 0, stream>>>(
        xw, asrc, adst, b_gat, offs, ssrc, yb);

    // GRU step t
    gemm_f32<<<dim3(G3 / GBN, (N_NODES + GBM - 1) / GBM), 256, 0, stream>>>(
        yb, W_ih, b_ih, gi, N_NODES, GHD, G3, 1);
    if (t > 0)
      gemm_f32<<<dim3(G3 / GBN, (N_NODES + GBM - 1) / GBM), 256, 0, stream>>>(
          ctx + (size_t)(t - 1) * N_NODES * GHD, W_hh, b_hh, gh, N_NODES, GHD, G3, 1);
    gru_combine<<<dim3((N_NODES * GHD + 255) / 256), 256, 0, stream>>>(
        gi, gh, (t > 0) ? ctx + (size_t)(t - 1) * N_NODES * GHD : nullptr, b_hh,
        ctx + (size_t)t * N_NODES * GHD, (t == 0) ? 1 : 0);
  }

  attn_kernel<<<dim3(N_NODES), 128, 0, stream>>>(
      ctx, W_att_in, W_att_out, W_cls, b_cls, out);
}

// Round 2
// 1479.823 us; speedup vs baseline: 2.1712x; 2.1712x over previous
//
#include <hip/hip_runtime.h>
#include <hip/hip_bf16.h>
#include <math.h>

#define N_NODES 20000
#define N_EDGES 160000
#define T_STEPS 8
#define F_INC   256
#define HEADS   4
#define CCH     128
#define KC      512   // HEADS*CCH
#define GHD     128
#define G3      384
#define SLOPE   0.2f

typedef unsigned short u16;
typedef __attribute__((ext_vector_type(8))) short bf16x8;
typedef __attribute__((ext_vector_type(4))) float f32x4;

__device__ __forceinline__ float leakyf(float x) { return x > 0.f ? x : SLOPE * x; }
__device__ __forceinline__ float b2f(u16 u) {
  union { unsigned int i; float f; } x; x.i = ((unsigned int)u) << 16; return x.f;
}
__device__ __forceinline__ u16 f2b(float f) {
  union { float f; unsigned int i; } u; u.f = f;
  unsigned int r = u.i + 0x7FFFu + ((u.i >> 16) & 1u);
  return (u16)(r >> 16);
}

// ---------------------------------------------------------------------------
// bf16 MFMA GEMM: C[M,Nt] = A[M,K] @ B^T (+bias), A (M,K) bf16, B (Nt,K) bf16.
// Block 256 thr / 4 waves, tile 128x128, BK=32, 16x16x32 MFMA, fp32 accum.
// XOR slot-swizzle on LDS so fragment ds_read_b128 is ~conflict-free.
// OBF=0: fp32 out, OBF=1: bf16 out. Requires K%32==0, Nt%128==0. M guarded.
// ---------------------------------------------------------------------------
template <int OBF>
__global__ __launch_bounds__(256) void gemm_bf16(
    const u16* __restrict__ A, const u16* __restrict__ B,
    const float* __restrict__ bias, void* __restrict__ Cout,
    int M, int K, int Nt)
{
  __shared__ u16 As[128][32];
  __shared__ u16 Bs[128][32];
  const int tid  = threadIdx.x;
  const int wave = tid >> 6, lane = tid & 63;
  const int wr = (wave >> 1) * 64, wc = (wave & 1) * 64;
  const int bm = blockIdx.y * 128, bn = blockIdx.x * 128;
  const int l15 = lane & 15, g = lane >> 4;

  f32x4 acc[4][4];
  #pragma unroll
  for (int m = 0; m < 4; ++m)
    #pragma unroll
    for (int n = 0; n < 4; ++n)
      #pragma unroll
      for (int j = 0; j < 4; ++j) acc[m][n][j] = 0.f;

  const int nK = K >> 5;
  for (int kt = 0; kt < nK; ++kt) {
    const int k0 = kt << 5;
    #pragma unroll
    for (int p = 0; p < 2; ++p) {
      int idx = tid + p * 256;
      int r = idx >> 2, s = idx & 3;
      int ss = s ^ ((r >> 1) & 3);
      int4 va = make_int4(0, 0, 0, 0);
      if (bm + r < M) va = *(const int4*)(A + (size_t)(bm + r) * K + k0 + s * 8);
      *(int4*)&As[r][ss * 8] = va;
      int4 vb = *(const int4*)(B + (size_t)(bn + r) * K + k0 + s * 8);
      *(int4*)&Bs[r][ss * 8] = vb;
    }
    __syncthreads();
    bf16x8 af[4], bfr[4];
    #pragma unroll
    for (int m = 0; m < 4; ++m) {
      int row = wr + m * 16 + l15;
      int slot = g ^ ((row >> 1) & 3);
      af[m] = *(const bf16x8*)&As[row][slot * 8];
      int rowb = wc + m * 16 + l15;
      int slotb = g ^ ((rowb >> 1) & 3);
      bfr[m] = *(const bf16x8*)&Bs[rowb][slotb * 8];
    }
    #pragma unroll
    for (int m = 0; m < 4; ++m)
      #pragma unroll
      for (int n = 0; n < 4; ++n)
        acc[m][n] = __builtin_amdgcn_mfma_f32_16x16x32_bf16(af[m], bfr[n], acc[m][n], 0, 0, 0);
    __syncthreads();
  }
  // epilogue: C/D layout col=lane&15, row=(lane>>4)*4+reg
  #pragma unroll
  for (int m = 0; m < 4; ++m) {
    int row0 = bm + wr + m * 16 + g * 4;
    #pragma unroll
    for (int n = 0; n < 4; ++n) {
      int col = bn + wc + n * 16 + l15;
      float bv = bias ? bias[col] : 0.f;
      #pragma unroll
      for (int j = 0; j < 4; ++j) {
        int row = row0 + j;
        if (row < M) {
          float v = acc[m][n][j] + bv;
          if (OBF) ((u16*)Cout)[(size_t)row * Nt + col] = f2b(v);
          else     ((float*)Cout)[(size_t)row * Nt + col] = v;
        }
      }
    }
  }
}

// ---------------------------------------------------------------------------
// fp32 -> bf16 convert (n % 4 == 0)
// ---------------------------------------------------------------------------
__global__ void convert_f32_bf16(const float* __restrict__ src, u16* __restrict__ dst, int n) {
  int i = (blockIdx.x * 256 + threadIdx.x) * 4;
  if (i >= n) return;
  float4 v = *(const float4*)(src + i);
  ushort4 o;
  o.x = f2b(v.x); o.y = f2b(v.y); o.z = f2b(v.z); o.w = f2b(v.w);
  *(ushort4*)(dst + i) = o;
}

// W_gat (K=256, N=512) row-major -> (N,K) bf16
__global__ void conv_transpose_wgat(const float* __restrict__ src, u16* __restrict__ dst) {
  int idx = blockIdx.x * 256 + threadIdx.x;
  if (idx >= KC * F_INC) return;
  int n = idx >> 8, k = idx & 255;
  dst[(size_t)n * F_INC + k] = f2b(src[(size_t)k * KC + n]);
}

// ---------------------------------------------------------------------------
// a_src[n,h] = <xw[n,h,:], att_src[h,:]>,  a_dst likewise. 1 wave / node.
// ---------------------------------------------------------------------------
__global__ __launch_bounds__(256) void a_kernel(
    const u16* __restrict__ xw, const float* __restrict__ att_s,
    const float* __restrict__ att_d, float* __restrict__ a_src,
    float* __restrict__ a_dst)
{
  const int wave = threadIdx.x >> 6;
  const int lane = threadIdx.x & 63;
  const int n = blockIdx.x * 4 + wave;
  if (n >= N_NODES) return;
  const int h = lane >> 4;
  const int i = lane & 15;
  float ps = 0.f, pd = 0.f;
  const u16* xr = xw + (size_t)n * KC + h * CCH;
  const float* as = att_s + h * CCH;
  const float* ad = att_d + h * CCH;
  #pragma unroll
  for (int j = 0; j < 8; ++j) {
    float x = b2f(xr[j * 16 + i]);
    ps = fmaf(x, as[j * 16 + i], ps);
    pd = fmaf(x, ad[j * 16 + i], pd);
  }
  #pragma unroll
  for (int m = 8; m >= 1; m >>= 1) {
    ps += __shfl_xor(ps, m);
    pd += __shfl_xor(pd, m);
  }
  if (i == 0) { a_src[n * 4 + h] = ps; a_dst[n * 4 + h] = pd; }
}

// ---------------------------------------------------------------------------
// Edge counting-sort by dst
// ---------------------------------------------------------------------------
__global__ void count_kernel(const int* __restrict__ dst, int* __restrict__ counts) {
  int e = blockIdx.x * blockDim.x + threadIdx.x;
  if (e < N_EDGES) atomicAdd(&counts[dst[e]], 1);
}

__global__ __launch_bounds__(1024) void scan_kernel(
    const int* __restrict__ counts, int* __restrict__ offs)
{
  __shared__ int buf[1024];
  const int tid = threadIdx.x;
  int carry = 0;
  for (int base = 0; base < N_NODES; base += 1024) {
    int i = base + tid;
    int v = (i < N_NODES) ? (counts[i] + 1) : 0;  // +1 = self loop
    buf[tid] = v;
    __syncthreads();
    for (int off = 1; off < 1024; off <<= 1) {
      int add = (tid >= off) ? buf[tid - off] : 0;
      __syncthreads();
      buf[tid] += add;
      __syncthreads();
    }
    int incl = buf[tid];
    if (i < N_NODES) offs[i] = carry + incl - v;  // exclusive
    carry += buf[1023];
    __syncthreads();
  }
  if (tid == 0) offs[N_NODES] = carry;
}

__global__ void scatter_kernel(const int* __restrict__ src, const int* __restrict__ dst,
                               const int* __restrict__ offs, int* __restrict__ cursor,
                               int* __restrict__ ssrc)
{
  int e = blockIdx.x * blockDim.x + threadIdx.x;
  if (e >= N_EDGES + N_NODES) return;
  int s, d;
  if (e < N_EDGES) { s = src[e]; d = dst[e]; }
  else             { s = d = e - N_EDGES; }       // self loops
  int pos = offs[d] + atomicAdd(&cursor[d], 1);
  ssrc[pos] = s;
}

// ---------------------------------------------------------------------------
// Per-dst softmax-weighted aggregation + head-mean + bias + leaky -> y (bf16)
// One 128-thread block per dst node. xw is bf16.
// ---------------------------------------------------------------------------
#define ECH 128
__global__ __launch_bounds__(128) void aggregate_kernel(
    const u16* __restrict__ xw, const float* __restrict__ a_src,
    const float* __restrict__ a_dst, const float* __restrict__ b_gat,
    const int* __restrict__ offs, const int* __restrict__ ssrc,
    u16* __restrict__ yout)
{
  const int d = blockIdx.x;
  const int tid = threadIdx.x;
  __shared__ int   s_src[ECH];
  __shared__ float s_w[ECH][4];
  __shared__ float s_m[4], s_s[4];
  __shared__ float s_acc[4][128];
  const int beg = offs[d], end = offs[d + 1];
  if (tid < 4) { s_m[tid] = -1e30f; s_s[tid] = 0.f; }
  __syncthreads();
  const float4 adv = *reinterpret_cast<const float4*>(&a_dst[d * 4]);
  const float ad[4] = {adv.x, adv.y, adv.z, adv.w};

  // phase 1: online segment max / sumexp per head
  for (int base = beg; base < end; base += ECH) {
    int cnt = min(ECH, end - base);
    if (tid < cnt) {
      int s = ssrc[base + tid];
      const float4 asv = *reinterpret_cast<const float4*>(&a_src[s * 4]);
      s_w[tid][0] = leakyf(asv.x + ad[0]);
      s_w[tid][1] = leakyf(asv.y + ad[1]);
      s_w[tid][2] = leakyf(asv.z + ad[2]);
      s_w[tid][3] = leakyf(asv.w + ad[3]);
    }
    __syncthreads();
    if (tid < 4) {
      int h = tid;
      float m = s_m[h], sm = s_s[h];
      for (int i2 = 0; i2 < cnt; ++i2) {
        float a = s_w[i2][h];
        if (a > m) { sm *= expf(m - a); m = a; }
        sm += expf(a - m);
      }
      s_m[h] = m; s_s[h] = sm;
    }
    __syncthreads();
  }
  const float m0 = s_m[0], m1 = s_m[1], m2 = s_m[2], m3 = s_m[3];
  const float i0 = 1.f / (s_s[0] + 1e-16f), i1 = 1.f / (s_s[1] + 1e-16f);
  const float i2_ = 1.f / (s_s[2] + 1e-16f), i3 = 1.f / (s_s[3] + 1e-16f);

  // phase 2: thread owns 4 contiguous dims of one head
  const int h  = tid >> 5;
  const int c0 = (tid & 31) << 2;
  float acc0 = 0.f, acc1 = 0.f, acc2 = 0.f, acc3 = 0.f;
  for (int base = beg; base < end; base += ECH) {
    int cnt = min(ECH, end - base);
    if (tid < cnt) {
      int s = ssrc[base + tid];
      s_src[tid] = s;
      const float4 asv = *reinterpret_cast<const float4*>(&a_src[s * 4]);
      s_w[tid][0] = expf(leakyf(asv.x + ad[0]) - m0) * i0;
      s_w[tid][1] = expf(leakyf(asv.y + ad[1]) - m1) * i1;
      s_w[tid][2] = expf(leakyf(asv.z + ad[2]) - m2) * i2_;
      s_w[tid][3] = expf(leakyf(asv.w + ad[3]) - m3) * i3;
    }
    __syncthreads();
    for (int e2 = 0; e2 < cnt; ++e2) {
      float w = s_w[e2][h];
      const ushort4 v = *(const ushort4*)(xw + (size_t)s_src[e2] * KC + h * CCH + c0);
      acc0 = fmaf(w, b2f(v.x), acc0);
      acc1 = fmaf(w, b2f(v.y), acc1);
      acc2 = fmaf(w, b2f(v.z), acc2);
      acc3 = fmaf(w, b2f(v.w), acc3);
    }
    __syncthreads();
  }
  s_acc[h][c0 + 0] = acc0; s_acc[h][c0 + 1] = acc1;
  s_acc[h][c0 + 2] = acc2; s_acc[h][c0 + 3] = acc3;
  __syncthreads();
  float v = (s_acc[0][tid] + s_acc[1][tid] + s_acc[2][tid] + s_acc[3][tid]) * 0.25f + b_gat[tid];
  yout[(size_t)d * GHD + tid] = f2b(leakyf(v));
}

// ---------------------------------------------------------------------------
// GRU elementwise combine. gi/gh bf16 (bias already added in GEMM).
// Writes ctx fp32 and h bf16.
// ---------------------------------------------------------------------------
__global__ void gru_combine(const u16* __restrict__ gi, const u16* __restrict__ gh,
                            const float* __restrict__ hprev, const float* __restrict__ b_hh,
                            float* __restrict__ hout, u16* __restrict__ hbf, int t0)
{
  int idx = blockIdx.x * 256 + threadIdx.x;
  if (idx >= N_NODES * GHD) return;
  int n = idx >> 7, c = idx & 127;
  size_t g = (size_t)n * G3;
  float ir = b2f(gi[g + c]), iz = b2f(gi[g + 128 + c]), in_ = b2f(gi[g + 256 + c]);
  float hr, hz, hn, hp;
  if (t0) { hr = b_hh[c]; hz = b_hh[128 + c]; hn = b_hh[256 + c]; hp = 0.f; }
  else    { hr = b2f(gh[g + c]); hz = b2f(gh[g + 128 + c]); hn = b2f(gh[g + 256 + c]); hp = hprev[idx]; }
  float r = 1.f / (1.f + expf(-(ir + hr)));
  float z = 1.f / (1.f + expf(-(iz + hz)));
  float nn = tanhf(in_ + r * hn);
  float h = (1.f - z) * nn + z * hp;
  hout[idx] = h;
  hbf[idx] = f2b(h);
}

// ---------------------------------------------------------------------------
// Temporal attention middle: scores + softmax + mix; emit combined bf16.
// One wave per node, lane owns dims (lane, lane+64). Register resident.
// ---------------------------------------------------------------------------
__global__ __launch_bounds__(256) void attn_mid(
    const float* __restrict__ ctx, const float* __restrict__ q,
    u16* __restrict__ comb)
{
  const int node = blockIdx.x * 4 + (threadIdx.x >> 6);
  const int lane = threadIdx.x & 63;
  if (node >= N_NODES) return;
  const float q0 = q[(size_t)node * GHD + lane];
  const float q1 = q[(size_t)node * GHD + 64 + lane];
  float c0[T_STEPS], c1[T_STEPS], w[T_STEPS];
  float mx = -1e30f;
  #pragma unroll
  for (int t = 0; t < T_STEPS; ++t) {
    const float* cr = ctx + ((size_t)t * N_NODES + node) * GHD;
    c0[t] = cr[lane]; c1[t] = cr[64 + lane];
    float p = q0 * c0[t] + q1 * c1[t];
    #pragma unroll
    for (int m = 32; m >= 1; m >>= 1) p += __shfl_xor(p, m);
    w[t] = p;
    mx = fmaxf(mx, p);
  }
  float s = 0.f;
  #pragma unroll
  for (int t = 0; t < T_STEPS; ++t) { w[t] = expf(w[t] - mx); s += w[t]; }
  const float inv = 1.f / s;
  float m0 = 0.f, m1 = 0.f;
  #pragma unroll
  for (int t = 0; t < T_STEPS; ++t) { m0 = fmaf(w[t], c0[t], m0); m1 = fmaf(w[t], c1[t], m1); }
  m0 *= inv; m1 *= inv;
  u16* cb = comb + (size_t)node * 2 * GHD;
  cb[lane]        = f2b(m0);
  cb[64 + lane]   = f2b(m1);
  cb[128 + lane]  = f2b(q0);
  cb[192 + lane]  = f2b(q1);
}

// ---------------------------------------------------------------------------
// tanh + leaky + classifier + log_softmax. One wave per node.
// ---------------------------------------------------------------------------
__global__ __launch_bounds__(256) void logits_kernel(
    const u16* __restrict__ ao, const float* __restrict__ W_cls,
    const float* __restrict__ b_cls, float* __restrict__ out)
{
  const int node = blockIdx.x * 4 + (threadIdx.x >> 6);
  const int lane = threadIdx.x & 63;
  if (node >= N_NODES) return;
  float o0 = leakyf(tanhf(b2f(ao[(size_t)node * GHD + lane])));
  float o1 = leakyf(tanhf(b2f(ao[(size_t)node * GHD + 64 + lane])));
  float p0 = o0 * W_cls[lane] + o1 * W_cls[64 + lane];
  float p1 = o0 * W_cls[128 + lane] + o1 * W_cls[192 + lane];
  #pragma unroll
  for (int m = 32; m >= 1; m >>= 1) { p0 += __shfl_xor(p0, m); p1 += __shfl_xor(p1, m); }
  if (lane == 0) {
    float l0 = p0 + b_cls[0];
    float l1 = p1 + b_cls[1];
    float mx = fmaxf(l0, l1);
    float lse = mx + logf(expf(l0 - mx) + expf(l1 - mx));
    out[(size_t)node * 2 + 0] = l0 - lse;
    out[(size_t)node * 2 + 1] = l1 - lse;
  }
}

// ---------------------------------------------------------------------------
extern "C" void kernel_launch(void* const* d_in, const int* in_sizes, int n_in,
                              void* d_out, int out_size, void* d_ws, size_t ws_size,
                              hipStream_t stream)
{
  const int*   graph     = (const int*)  d_in[0];
  const float* fts       = (const float*)d_in[1];
  const float* W_gat     = (const float*)d_in[3];
  const float* att_src   = (const float*)d_in[4];
  const float* att_dst   = (const float*)d_in[5];
  const float* b_gat     = (const float*)d_in[6];
  const float* W_ih      = (const float*)d_in[7];
  const float* W_hh      = (const float*)d_in[8];
  const float* b_ih      = (const float*)d_in[9];
  const float* b_hh      = (const float*)d_in[10];
  const float* W_att_in  = (const float*)d_in[11];
  const float* W_att_out = (const float*)d_in[12];
  const float* W_cls     = (const float*)d_in[13];
  const float* b_cls     = (const float*)d_in[14];
  float* out = (float*)d_out;

  char* ws = (char*)d_ws;
  size_t off = 0;
  auto alloc = [&](size_t bytes) {
    void* p = ws + off;
    off = (off + bytes + 255) & ~(size_t)255;
    return p;
  };
  u16*   fbf   = (u16*)alloc((size_t)N_NODES * F_INC * 2);          // per-t fts bf16
  u16*   wgatT = (u16*)alloc((size_t)KC * F_INC * 2);               // (512,256)
  u16*   wihb  = (u16*)alloc((size_t)G3 * GHD * 2);
  u16*   whhb  = (u16*)alloc((size_t)G3 * GHD * 2);
  u16*   winb  = (u16*)alloc((size_t)GHD * GHD * 2);
  u16*   woutb = (u16*)alloc((size_t)GHD * 2 * GHD * 2);
  u16*   xw    = (u16*)alloc((size_t)N_NODES * KC * 2);             // 20.5 MB
  float* asrc  = (float*)alloc((size_t)N_NODES * 4 * 4);
  float* adst  = (float*)alloc((size_t)N_NODES * 4 * 4);
  u16*   ybf   = (u16*)alloc((size_t)N_NODES * GHD * 2);
  u16*   gi    = (u16*)alloc((size_t)N_NODES * G3 * 2);
  u16*   gh    = (u16*)alloc((size_t)N_NODES * G3 * 2);
  float* ctx   = (float*)alloc((size_t)T_STEPS * N_NODES * GHD * 4); // 82 MB
  u16*   hbf   = (u16*)alloc((size_t)N_NODES * GHD * 2);            // current h bf16
  float* qf    = (float*)alloc((size_t)N_NODES * GHD * 4);
  u16*   comb  = (u16*)alloc((size_t)N_NODES * 2 * GHD * 2);
  u16*   aob   = (u16*)alloc((size_t)N_NODES * GHD * 2);
  int* counts  = (int*)alloc((size_t)N_NODES * 4);
  int* offs    = (int*)alloc((size_t)(N_NODES + 1) * 4);
  int* cursor  = (int*)alloc((size_t)N_NODES * 4);
  int* ssrc    = (int*)alloc((size_t)(N_EDGES + N_NODES) * 4);

  const int MB = (N_NODES + 127) / 128;  // 157

  // weight conversions (once per call)
  conv_transpose_wgat<<<dim3((KC * F_INC + 255) / 256), 256, 0, stream>>>(W_gat, wgatT);
  convert_f32_bf16<<<dim3((G3 * GHD / 4 + 255) / 256), 256, 0, stream>>>(W_ih, wihb, G3 * GHD);
  convert_f32_bf16<<<dim3((G3 * GHD / 4 + 255) / 256), 256, 0, stream>>>(W_hh, whhb, G3 * GHD);
  convert_f32_bf16<<<dim3((GHD * GHD / 4 + 255) / 256), 256, 0, stream>>>(W_att_in, winb, GHD * GHD);
  convert_f32_bf16<<<dim3((GHD * 2 * GHD / 4 + 255) / 256), 256, 0, stream>>>(W_att_out, woutb, GHD * 2 * GHD);

  for (int t = 0; t < T_STEPS; ++t) {
    const float* ft  = fts + (size_t)t * N_NODES * F_INC;
    const int* esrc  = graph + (size_t)t * 2 * N_EDGES;
    const int* edst  = esrc + N_EDGES;

    convert_f32_bf16<<<dim3((N_NODES * F_INC / 4 + 255) / 256), 256, 0, stream>>>(
        ft, fbf, N_NODES * F_INC);

    // GAT
    gemm_bf16<1><<<dim3(KC / 128, MB), 256, 0, stream>>>(
        fbf, wgatT, nullptr, xw, N_NODES, F_INC, KC);
    a_kernel<<<dim3(N_NODES / 4), 256, 0, stream>>>(xw, att_src, att_dst, asrc, adst);
    hipMemsetAsync(counts, 0, (size_t)N_NODES * 4, stream);
    count_kernel<<<dim3((N_EDGES + 255) / 256), 256, 0, stream>>>(edst, counts);
    scan_kernel<<<dim3(1), 1024, 0, stream>>>(counts, offs);
    hipMemsetAsync(cursor, 0, (size_t)N_NODES * 4, stream);
    scatter_kernel<<<dim3((N_EDGES + N_NODES + 255) / 256), 256, 0, stream>>>(
        esrc, edst, offs, cursor, ssrc);
    aggregate_kernel<<<dim3(N_NODES), 128, 0, stream>>>(
        xw, asrc, adst, b_gat, offs, ssrc, ybf);

    // GRU step t
    gemm_bf16<1><<<dim3(G3 / 128, MB), 256, 0, stream>>>(
        ybf, wihb, b_ih, gi, N_NODES, GHD, G3);
    if (t > 0)
      gemm_bf16<1><<<dim3(G3 / 128, MB), 256, 0, stream>>>(
          hbf, whhb, b_hh, gh, N_NODES, GHD, G3);
    gru_combine<<<dim3((N_NODES * GHD + 255) / 256), 256, 0, stream>>>(
        gi, gh, (t > 0) ? ctx + (size_t)(t - 1) * N_NODES * GHD : nullptr, b_hh,
        ctx + (size_t)t * N_NODES * GHD, hbf, (t == 0) ? 1 : 0);
  }

  // temporal attention tail
  gemm_bf16<0><<<dim3(1, MB), 256, 0, stream>>>(hbf, winb, nullptr, qf, N_NODES, GHD, GHD);
  attn_mid<<<dim3((N_NODES + 3) / 4), 256, 0, stream>>>(ctx, qf, comb);
  gemm_bf16<1><<<dim3(1, MB), 256, 0, stream>>>(comb, woutb, nullptr, aob, N_NODES, 2 * GHD, GHD);
  logits_kernel<<<dim3((N_NODES + 3) / 4), 256, 0, stream>>>(aob, W_cls, b_cls, out);
}

// Round 3
// 891.335 us; speedup vs baseline: 3.6047x; 1.6602x over previous
//
#include <hip/hip_runtime.h>
#include <hip/hip_bf16.h>
#include <math.h>

#define N_NODES 20000
#define N_EDGES 160000
#define T_STEPS 8
#define F_INC   256
#define HEADS   4
#define CCH     128
#define KC      512   // HEADS*CCH
#define GHD     128
#define G3      384
#define SLOPE   0.2f
#define SEG     (N_EDGES + N_NODES)   // edges + self loops per t

typedef unsigned short u16;
typedef __attribute__((ext_vector_type(8))) short bf16x8;
typedef __attribute__((ext_vector_type(4))) float f32x4;

__device__ __forceinline__ float leakyf(float x) { return x > 0.f ? x : SLOPE * x; }
__device__ __forceinline__ float b2f(u16 u) {
  union { unsigned int i; float f; } x; x.i = ((unsigned int)u) << 16; return x.f;
}
__device__ __forceinline__ u16 f2b(float f) {
  union { float f; unsigned int i; } u; u.f = f;
  unsigned int r = u.i + 0x7FFFu + ((u.i >> 16) & 1u);
  return (u16)(r >> 16);
}
__device__ __forceinline__ float sigf(float x) { return 1.f / (1.f + expf(-x)); }

// ---------------------------------------------------------------------------
// bf16 MFMA GEMM: C[M,Nt] = A[M,K] @ B^T (+bias). B (Nt,K) bf16.
// AT=float: A fp32, converted to bf16 during LDS staging. AT=u16: A bf16.
// FUSE=1 (xw gemm only): also emit a_src/a_dst = <C_tile_row, att[head]> —
// valid because each 128-col tile is exactly one head.
// ---------------------------------------------------------------------------
template <int OBF, int FUSE, typename AT>
__global__ __launch_bounds__(256) void gemm_bf16(
    const AT* __restrict__ A, const u16* __restrict__ B,
    const float* __restrict__ bias, void* __restrict__ Cout,
    int M, int K, int Nt,
    const float* __restrict__ attS, const float* __restrict__ attD,
    float* __restrict__ asrc, float* __restrict__ adst)
{
  __shared__ u16 As[128][32];
  __shared__ u16 Bs[128][32];
  __shared__ float s_as[128], s_ad[128];
  const int tid  = threadIdx.x;
  const int wave = tid >> 6, lane = tid & 63;
  const int wr = (wave >> 1) * 64, wc = (wave & 1) * 64;
  const int bm = blockIdx.y * 128, bn = blockIdx.x * 128;
  const int l15 = lane & 15, g = lane >> 4;

  if (FUSE && tid < 128) { s_as[tid] = 0.f; s_ad[tid] = 0.f; }

  f32x4 acc[4][4];
  #pragma unroll
  for (int m = 0; m < 4; ++m)
    #pragma unroll
    for (int n = 0; n < 4; ++n)
      #pragma unroll
      for (int j = 0; j < 4; ++j) acc[m][n][j] = 0.f;

  const int nK = K >> 5;
  for (int kt = 0; kt < nK; ++kt) {
    const int k0 = kt << 5;
    #pragma unroll
    for (int p = 0; p < 2; ++p) {
      int idx = tid + p * 256;
      int r = idx >> 2, s = idx & 3;
      int ss = s ^ ((r >> 1) & 3);
      // A slot (8 elems)
      if (sizeof(AT) == 4) {
        const float* Af = (const float*)A;
        float4 v0 = make_float4(0.f,0.f,0.f,0.f), v1 = v0;
        if (bm + r < M) {
          const float* p8 = Af + (size_t)(bm + r) * K + k0 + s * 8;
          v0 = *(const float4*)p8; v1 = *(const float4*)(p8 + 4);
        }
        u16* dstp = &As[r][ss * 8];
        dstp[0]=f2b(v0.x); dstp[1]=f2b(v0.y); dstp[2]=f2b(v0.z); dstp[3]=f2b(v0.w);
        dstp[4]=f2b(v1.x); dstp[5]=f2b(v1.y); dstp[6]=f2b(v1.z); dstp[7]=f2b(v1.w);
      } else {
        const u16* Ab = (const u16*)A;
        int4 va = make_int4(0,0,0,0);
        if (bm + r < M) va = *(const int4*)(Ab + (size_t)(bm + r) * K + k0 + s * 8);
        *(int4*)&As[r][ss * 8] = va;
      }
      int4 vb = *(const int4*)(B + (size_t)(bn + r) * K + k0 + s * 8);
      *(int4*)&Bs[r][ss * 8] = vb;
    }
    __syncthreads();
    bf16x8 af[4], bfr[4];
    #pragma unroll
    for (int m = 0; m < 4; ++m) {
      int row = wr + m * 16 + l15;
      af[m] = *(const bf16x8*)&As[row][(g ^ ((row >> 1) & 3)) * 8];
      int rowb = wc + m * 16 + l15;
      bfr[m] = *(const bf16x8*)&Bs[rowb][(g ^ ((rowb >> 1) & 3)) * 8];
    }
    #pragma unroll
    for (int m = 0; m < 4; ++m)
      #pragma unroll
      for (int n = 0; n < 4; ++n)
        acc[m][n] = __builtin_amdgcn_mfma_f32_16x16x32_bf16(af[m], bfr[n], acc[m][n], 0, 0, 0);
    __syncthreads();
  }
  // epilogue: C/D layout col=lane&15, row=(lane>>4)*4+reg
  #pragma unroll
  for (int m = 0; m < 4; ++m) {
    int row0 = bm + wr + m * 16 + g * 4;
    #pragma unroll
    for (int n = 0; n < 4; ++n) {
      int col = bn + wc + n * 16 + l15;
      float bv = bias ? bias[col] : 0.f;
      #pragma unroll
      for (int j = 0; j < 4; ++j) {
        int row = row0 + j;
        if (row < M) {
          float v = acc[m][n][j] + bv;
          if (OBF) ((u16*)Cout)[(size_t)row * Nt + col] = f2b(v);
          else     ((float*)Cout)[(size_t)row * Nt + col] = v;
        }
      }
    }
  }
  if (FUSE) {
    // per-row dot with att vectors over this block's 128 cols (= one head)
    float ps[4][4], pd[4][4];
    #pragma unroll
    for (int m = 0; m < 4; ++m)
      #pragma unroll
      for (int j = 0; j < 4; ++j) { ps[m][j] = 0.f; pd[m][j] = 0.f; }
    #pragma unroll
    for (int n = 0; n < 4; ++n) {
      int cl = wc + n * 16 + l15;
      float ws = attS[bn + cl], wd = attD[bn + cl];
      #pragma unroll
      for (int m = 0; m < 4; ++m)
        #pragma unroll
        for (int j = 0; j < 4; ++j) {
          ps[m][j] = fmaf(acc[m][n][j], ws, ps[m][j]);
          pd[m][j] = fmaf(acc[m][n][j], wd, pd[m][j]);
        }
    }
    #pragma unroll
    for (int m = 0; m < 4; ++m)
      #pragma unroll
      for (int j = 0; j < 4; ++j)
        #pragma unroll
        for (int msk = 8; msk >= 1; msk >>= 1) {
          ps[m][j] += __shfl_xor(ps[m][j], msk);
          pd[m][j] += __shfl_xor(pd[m][j], msk);
        }
    if (l15 == 0) {
      #pragma unroll
      for (int m = 0; m < 4; ++m)
        #pragma unroll
        for (int j = 0; j < 4; ++j) {
          atomicAdd(&s_as[wr + m * 16 + g * 4 + j], ps[m][j]);
          atomicAdd(&s_ad[wr + m * 16 + g * 4 + j], pd[m][j]);
        }
    }
    __syncthreads();
    if (tid < 128) {
      int row = bm + tid;
      if (row < M) {
        int h = bn >> 7;
        asrc[(size_t)row * 4 + h] = s_as[tid];
        adst[(size_t)row * 4 + h] = s_ad[tid];
      }
    }
  }
}

// ---------------------------------------------------------------------------
// small fp32->bf16 weight converts
// ---------------------------------------------------------------------------
__global__ void convert_f32_bf16(const float* __restrict__ src, u16* __restrict__ dst, int n) {
  int i = (blockIdx.x * 256 + threadIdx.x) * 4;
  if (i >= n) return;
  float4 v = *(const float4*)(src + i);
  ushort4 o;
  o.x = f2b(v.x); o.y = f2b(v.y); o.z = f2b(v.z); o.w = f2b(v.w);
  *(ushort4*)(dst + i) = o;
}

__global__ void conv_transpose_wgat(const float* __restrict__ src, u16* __restrict__ dst) {
  int idx = blockIdx.x * 256 + threadIdx.x;
  if (idx >= KC * F_INC) return;
  int n = idx >> 8, k = idx & 255;
  dst[(size_t)n * F_INC + k] = f2b(src[(size_t)k * KC + n]);
}

// ---------------------------------------------------------------------------
// Batched edge counting-sort (all T at once)
// ---------------------------------------------------------------------------
__global__ void count_kernel(const int* __restrict__ graph, int* __restrict__ counts) {
  int e = blockIdx.x * 256 + threadIdx.x;
  int t = blockIdx.y;
  if (e < N_EDGES) {
    int d = graph[(size_t)t * 2 * N_EDGES + N_EDGES + e];
    atomicAdd(&counts[t * N_NODES + d], 1);
  }
}

__global__ __launch_bounds__(1024) void scan_kernel(
    const int* __restrict__ counts, int* __restrict__ offs)
{
  const int t = blockIdx.x;
  const int tid = threadIdx.x, lane = tid & 63, w = tid >> 6;
  __shared__ int s_wt[16];
  int carry = 0;
  const int base_abs = t * SEG;
  for (int base = 0; base < N_NODES; base += 1024) {
    int i = base + tid;
    int v = (i < N_NODES) ? (counts[t * N_NODES + i] + 1) : 0;  // +1 self loop
    int x = v;
    #pragma unroll
    for (int d = 1; d < 64; d <<= 1) {
      int nvl = __shfl_up(x, d, 64);
      if (lane >= d) x += nvl;
    }
    if (lane == 63) s_wt[w] = x;
    __syncthreads();
    if (tid < 16) {
      int y = s_wt[tid];
      #pragma unroll
      for (int d = 1; d < 16; d <<= 1) {
        int nvl = __shfl_up(y, d, 64);
        if (tid >= d) y += nvl;
      }
      s_wt[tid] = y;
    }
    __syncthreads();
    int wbase = (w > 0) ? s_wt[w - 1] : 0;
    int total = s_wt[15];
    if (i < N_NODES) offs[t * (N_NODES + 1) + i] = base_abs + carry + wbase + x - v;
    carry += total;
    __syncthreads();
  }
  if (tid == 0) offs[t * (N_NODES + 1) + N_NODES] = base_abs + carry;
}

__global__ void scatter_kernel(const int* __restrict__ graph, const int* __restrict__ offs,
                               int* __restrict__ cursor, int* __restrict__ ssrc)
{
  int i = blockIdx.x * 256 + threadIdx.x;
  int t = blockIdx.y;
  if (i >= SEG) return;
  int s, d;
  if (i < N_EDGES) {
    s = graph[(size_t)t * 2 * N_EDGES + i];
    d = graph[(size_t)t * 2 * N_EDGES + N_EDGES + i];
  } else {
    s = d = i - N_EDGES;
  }
  int pos = offs[t * (N_NODES + 1) + d] + atomicAdd(&cursor[t * N_NODES + d], 1);
  ssrc[pos] = s;
}

// ---------------------------------------------------------------------------
// Batched aggregate: one wave per (t, node); lane owns 8 contiguous channels
// (all within head lane>>4). 16B coalesced xw row loads, softmax via shfl.
// ---------------------------------------------------------------------------
__global__ __launch_bounds__(256) void aggregate_kernel(
    const u16* __restrict__ xw, const float* __restrict__ a_src,
    const float* __restrict__ a_dst, const float* __restrict__ b_gat,
    const int* __restrict__ offs, const int* __restrict__ ssrc,
    u16* __restrict__ yout)
{
  const int wv = threadIdx.x >> 6, lane = threadIdx.x & 63;
  const int nd = blockIdx.x * 4 + wv;
  const int t  = blockIdx.y;
  __shared__ float s_w[4][64][4];
  __shared__ int   s_s[4][64];
  const int ob = t * (N_NODES + 1) + nd;
  const int beg = offs[ob], end = offs[ob + 1];
  const size_t rowbase = (size_t)t * N_NODES;
  const float4 adv = *(const float4*)&a_dst[(rowbase + nd) * 4];
  const int hl = lane >> 4;

  // pass 1: online max & sumexp per head, wave-parallel over edges
  float m0=-INFINITY, m1=-INFINITY, m2=-INFINITY, m3=-INFINITY;
  float s0=0.f, s1=0.f, s2=0.f, s3=0.f;
  for (int base = beg; base < end; base += 64) {
    int e = base + lane;
    float a0=-INFINITY, a1=-INFINITY, a2=-INFINITY, a3=-INFINITY;
    if (e < end) {
      int s = ssrc[e];
      float4 av = *(const float4*)&a_src[(rowbase + s) * 4];
      a0 = leakyf(av.x + adv.x); a1 = leakyf(av.y + adv.y);
      a2 = leakyf(av.z + adv.z); a3 = leakyf(av.w + adv.w);
    }
    float c0=a0, c1=a1, c2=a2, c3=a3;
    #pragma unroll
    for (int msk = 32; msk >= 1; msk >>= 1) {
      c0 = fmaxf(c0, __shfl_xor(c0, msk)); c1 = fmaxf(c1, __shfl_xor(c1, msk));
      c2 = fmaxf(c2, __shfl_xor(c2, msk)); c3 = fmaxf(c3, __shfl_xor(c3, msk));
    }
    float n0 = fmaxf(m0, c0), n1 = fmaxf(m1, c1), n2 = fmaxf(m2, c2), n3 = fmaxf(m3, c3);
    float e0 = expf(a0 - n0), e1 = expf(a1 - n1), e2 = expf(a2 - n2), e3 = expf(a3 - n3);
    #pragma unroll
    for (int msk = 32; msk >= 1; msk >>= 1) {
      e0 += __shfl_xor(e0, msk); e1 += __shfl_xor(e1, msk);
      e2 += __shfl_xor(e2, msk); e3 += __shfl_xor(e3, msk);
    }
    s0 = s0 * expf(m0 - n0) + e0; s1 = s1 * expf(m1 - n1) + e1;
    s2 = s2 * expf(m2 - n2) + e2; s3 = s3 * expf(m3 - n3) + e3;
    m0 = n0; m1 = n1; m2 = n2; m3 = n3;
  }
  const float i0 = 1.f/(s0+1e-16f), i1 = 1.f/(s1+1e-16f);
  const float i2 = 1.f/(s2+1e-16f), i3 = 1.f/(s3+1e-16f);

  // pass 2: weights to LDS, then weighted accumulate of xw rows
  float acc[8] = {0.f,0.f,0.f,0.f,0.f,0.f,0.f,0.f};
  for (int base = beg; base < end; base += 64) {
    int e = base + lane;
    if (e < end) {
      int s = ssrc[e];
      float4 av = *(const float4*)&a_src[(rowbase + s) * 4];
      s_s[wv][lane] = s;
      s_w[wv][lane][0] = expf(leakyf(av.x + adv.x) - m0) * i0;
      s_w[wv][lane][1] = expf(leakyf(av.y + adv.y) - m1) * i1;
      s_w[wv][lane][2] = expf(leakyf(av.z + adv.z) - m2) * i2;
      s_w[wv][lane][3] = expf(leakyf(av.w + adv.w) - m3) * i3;
    }
    int cnt = min(64, end - base);
    for (int e2 = 0; e2 < cnt; ++e2) {
      float w = s_w[wv][e2][hl];
      const int4 xi = *(const int4*)&xw[(rowbase + s_s[wv][e2]) * KC + lane * 8];
      acc[0] = fmaf(w, b2f((u16)(xi.x & 0xffff)), acc[0]);
      acc[1] = fmaf(w, b2f((u16)((unsigned)xi.x >> 16)), acc[1]);
      acc[2] = fmaf(w, b2f((u16)(xi.y & 0xffff)), acc[2]);
      acc[3] = fmaf(w, b2f((u16)((unsigned)xi.y >> 16)), acc[3]);
      acc[4] = fmaf(w, b2f((u16)(xi.z & 0xffff)), acc[4]);
      acc[5] = fmaf(w, b2f((u16)(xi.z >> 16) & 0xffff), acc[5]);
      acc[6] = fmaf(w, b2f((u16)(xi.w & 0xffff)), acc[6]);
      acc[7] = fmaf(w, b2f((u16)((unsigned)xi.w >> 16)), acc[7]);
    }
  }
  // head mean: lanes {l, l^16, l^32, l^48} hold same within-head channels
  #pragma unroll
  for (int k = 0; k < 8; ++k) {
    acc[k] += __shfl_xor(acc[k], 16);
    acc[k] += __shfl_xor(acc[k], 32);
  }
  if (lane < 16) {
    bf16x8 ov;
    #pragma unroll
    for (int k = 0; k < 8; ++k) {
      float v = acc[k] * 0.25f + b_gat[lane * 8 + k];
      ov[k] = (short)f2b(leakyf(v));
    }
    *(bf16x8*)&yout[(rowbase + nd) * GHD + lane * 8] = ov;
  }
}

// ---------------------------------------------------------------------------
// GRU t=0 combine (h_prev = 0, gh = b_hh)
// ---------------------------------------------------------------------------
__global__ void gru_combine0(const u16* __restrict__ gi_t, const float* __restrict__ b_hh,
                             float* __restrict__ ctx0, u16* __restrict__ hbf)
{
  int idx = blockIdx.x * 256 + threadIdx.x;
  if (idx >= N_NODES * GHD) return;
  int n = idx >> 7, c = idx & 127;
  size_t gb = (size_t)n * G3;
  float ir = b2f(gi_t[gb + c]), iz = b2f(gi_t[gb + 128 + c]), in_ = b2f(gi_t[gb + 256 + c]);
  float r = sigf(ir + b_hh[c]);
  float z = sigf(iz + b_hh[128 + c]);
  float nn = tanhf(in_ + r * b_hh[256 + c]);
  float h = (1.f - z) * nn;
  ctx0[idx] = h;
  hbf[idx] = f2b(h);
}

// ---------------------------------------------------------------------------
// Fused gh-GEMM (64x384 tile, whole gate row per block) + GRU combine.
// 4 waves: wave wv covers cols [wv*96, wv*96+96). gh goes through LDS (bf16,
// XOR slot-swizzled), never to HBM.
// ---------------------------------------------------------------------------
__global__ __launch_bounds__(256) void gru_fused(
    const u16* __restrict__ hprev_bf, const u16* __restrict__ Whh,
    const float* __restrict__ b_hh, const u16* __restrict__ gi_t,
    const float* __restrict__ ctx_prev, float* __restrict__ ctx_out,
    u16* __restrict__ hbf_out)
{
  __shared__ u16 lds[64 * 384];                       // 48 KB, dual-purpose
  u16 (*As)[32] = (u16(*)[32])lds;                    // 64 x 32
  u16 (*Bs)[32] = (u16(*)[32])(lds + 64 * 32);        // 384 x 32
  const int tid = threadIdx.x, lane = tid & 63, wv = tid >> 6;
  const int l15 = lane & 15, g = lane >> 4;
  const int bm = blockIdx.x * 64;

  f32x4 acc[4][6];
  #pragma unroll
  for (int m = 0; m < 4; ++m)
    #pragma unroll
    for (int n = 0; n < 6; ++n)
      #pragma unroll
      for (int j = 0; j < 4; ++j) acc[m][n][j] = 0.f;

  #pragma unroll
  for (int kt = 0; kt < 4; ++kt) {
    { // A: 64 rows x 4 slots
      int r = tid >> 2, s = tid & 3, ss = s ^ ((r >> 1) & 3);
      int gr = bm + r;
      int4 va = make_int4(0, 0, 0, 0);
      if (gr < N_NODES) va = *(const int4*)&hprev_bf[(size_t)gr * GHD + kt * 32 + s * 8];
      *(int4*)&As[r][ss * 8] = va;
    }
    #pragma unroll
    for (int p = 0; p < 6; ++p) { // B: 384 rows x 4 slots
      int idx = tid + p * 256;
      int r = idx >> 2, s = idx & 3, ss = s ^ ((r >> 1) & 3);
      *(int4*)&Bs[r][ss * 8] = *(const int4*)&Whh[(size_t)r * GHD + kt * 32 + s * 8];
    }
    __syncthreads();
    bf16x8 af[4], bfr[6];
    #pragma unroll
    for (int m = 0; m < 4; ++m) {
      int row = m * 16 + l15;
      af[m] = *(const bf16x8*)&As[row][(g ^ ((row >> 1) & 3)) * 8];
    }
    #pragma unroll
    for (int n = 0; n < 6; ++n) {
      int row = wv * 96 + n * 16 + l15;
      bfr[n] = *(const bf16x8*)&Bs[row][(g ^ ((row >> 1) & 3)) * 8];
    }
    #pragma unroll
    for (int m = 0; m < 4; ++m)
      #pragma unroll
      for (int n = 0; n < 6; ++n)
        acc[m][n] = __builtin_amdgcn_mfma_f32_16x16x32_bf16(af[m], bfr[n], acc[m][n], 0, 0, 0);
    __syncthreads();
  }
  // gh (+b_hh) -> LDS bf16, swizzled: slot' = (c>>3) ^ (r&7)
  #pragma unroll
  for (int m = 0; m < 4; ++m)
    #pragma unroll
    for (int n = 0; n < 6; ++n) {
      int c = wv * 96 + n * 16 + l15;
      float bb = b_hh[c];
      #pragma unroll
      for (int j = 0; j < 4; ++j) {
        int r = m * 16 + g * 4 + j;
        lds[r * 384 + (((c >> 3) ^ (r & 7)) << 3) + (c & 7)] = f2b(acc[m][n][j] + bb);
      }
    }
  __syncthreads();
  // combine: thread -> row tid>>2, 32 channels (tid&3)*32..+31
  {
    int r = tid >> 2, gr = bm + r;
    if (gr < N_NODES) {
      const int cg = (tid & 3) * 32;
      const size_t gb = (size_t)gr * G3;
      const size_t cb = (size_t)gr * GHD;
      #pragma unroll
      for (int q = 0; q < 4; ++q) {
        int c0 = cg + q * 8;
        int sl0 = ((c0 >> 3) ^ (r & 7));
        int sl1 = (((128 + c0) >> 3) ^ (r & 7));
        int sl2 = (((256 + c0) >> 3) ^ (r & 7));
        bf16x8 hr8 = *(bf16x8*)&lds[r * 384 + sl0 * 8];
        bf16x8 hz8 = *(bf16x8*)&lds[r * 384 + sl1 * 8];
        bf16x8 hn8 = *(bf16x8*)&lds[r * 384 + sl2 * 8];
        bf16x8 ir8 = *(const bf16x8*)&gi_t[gb + c0];
        bf16x8 iz8 = *(const bf16x8*)&gi_t[gb + 128 + c0];
        bf16x8 in8 = *(const bf16x8*)&gi_t[gb + 256 + c0];
        float4 hp0 = *(const float4*)&ctx_prev[cb + c0];
        float4 hp1 = *(const float4*)&ctx_prev[cb + c0 + 4];
        float hp[8] = {hp0.x, hp0.y, hp0.z, hp0.w, hp1.x, hp1.y, hp1.z, hp1.w};
        float cv[8];
        bf16x8 hv;
        #pragma unroll
        for (int k = 0; k < 8; ++k) {
          float rr = sigf(b2f((u16)ir8[k]) + b2f((u16)hr8[k]));
          float zz = sigf(b2f((u16)iz8[k]) + b2f((u16)hz8[k]));
          float nn = tanhf(b2f((u16)in8[k]) + rr * b2f((u16)hn8[k]));
          float h = (1.f - zz) * nn + zz * hp[k];
          cv[k] = h;
          hv[k] = (short)f2b(h);
        }
        *(float4*)&ctx_out[cb + c0]     = make_float4(cv[0], cv[1], cv[2], cv[3]);
        *(float4*)&ctx_out[cb + c0 + 4] = make_float4(cv[4], cv[5], cv[6], cv[7]);
        *(bf16x8*)&hbf_out[cb + c0] = hv;
      }
    }
  }
}

// ---------------------------------------------------------------------------
// Temporal attention middle: scores + softmax + mix. One wave / node.
// ---------------------------------------------------------------------------
__global__ __launch_bounds__(256) void attn_mid(
    const float* __restrict__ ctx, const float* __restrict__ q,
    u16* __restrict__ comb)
{
  const int node = blockIdx.x * 4 + (threadIdx.x >> 6);
  const int lane = threadIdx.x & 63;
  if (node >= N_NODES) return;
  const float q0 = q[(size_t)node * GHD + lane];
  const float q1 = q[(size_t)node * GHD + 64 + lane];
  float c0[T_STEPS], c1[T_STEPS], w[T_STEPS];
  float mx = -1e30f;
  #pragma unroll
  for (int t = 0; t < T_STEPS; ++t) {
    const float* cr = ctx + ((size_t)t * N_NODES + node) * GHD;
    c0[t] = cr[lane]; c1[t] = cr[64 + lane];
    float p = q0 * c0[t] + q1 * c1[t];
    #pragma unroll
    for (int m = 32; m >= 1; m >>= 1) p += __shfl_xor(p, m);
    w[t] = p;
    mx = fmaxf(mx, p);
  }
  float s = 0.f;
  #pragma unroll
  for (int t = 0; t < T_STEPS; ++t) { w[t] = expf(w[t] - mx); s += w[t]; }
  const float inv = 1.f / s;
  float m0 = 0.f, m1 = 0.f;
  #pragma unroll
  for (int t = 0; t < T_STEPS; ++t) { m0 = fmaf(w[t], c0[t], m0); m1 = fmaf(w[t], c1[t], m1); }
  m0 *= inv; m1 *= inv;
  u16* cb = comb + (size_t)node * 2 * GHD;
  cb[lane]       = f2b(m0);
  cb[64 + lane]  = f2b(m1);
  cb[128 + lane] = f2b(q0);
  cb[192 + lane] = f2b(q1);
}

// ---------------------------------------------------------------------------
// tanh + leaky + classifier + log_softmax. One wave / node.
// ---------------------------------------------------------------------------
__global__ __launch_bounds__(256) void logits_kernel(
    const u16* __restrict__ ao, const float* __restrict__ W_cls,
    const float* __restrict__ b_cls, float* __restrict__ out)
{
  const int node = blockIdx.x * 4 + (threadIdx.x >> 6);
  const int lane = threadIdx.x & 63;
  if (node >= N_NODES) return;
  float o0 = leakyf(tanhf(b2f(ao[(size_t)node * GHD + lane])));
  float o1 = leakyf(tanhf(b2f(ao[(size_t)node * GHD + 64 + lane])));
  float p0 = o0 * W_cls[lane] + o1 * W_cls[64 + lane];
  float p1 = o0 * W_cls[128 + lane] + o1 * W_cls[192 + lane];
  #pragma unroll
  for (int m = 32; m >= 1; m >>= 1) { p0 += __shfl_xor(p0, m); p1 += __shfl_xor(p1, m); }
  if (lane == 0) {
    float l0 = p0 + b_cls[0];
    float l1 = p1 + b_cls[1];
    float mx = fmaxf(l0, l1);
    float lse = mx + logf(expf(l0 - mx) + expf(l1 - mx));
    out[(size_t)node * 2 + 0] = l0 - lse;
    out[(size_t)node * 2 + 1] = l1 - lse;
  }
}

// ---------------------------------------------------------------------------
extern "C" void kernel_launch(void* const* d_in, const int* in_sizes, int n_in,
                              void* d_out, int out_size, void* d_ws, size_t ws_size,
                              hipStream_t stream)
{
  const int*   graph     = (const int*)  d_in[0];
  const float* fts       = (const float*)d_in[1];
  const float* W_gat     = (const float*)d_in[3];
  const float* att_src   = (const float*)d_in[4];
  const float* att_dst   = (const float*)d_in[5];
  const float* b_gat     = (const float*)d_in[6];
  const float* W_ih      = (const float*)d_in[7];
  const float* W_hh      = (const float*)d_in[8];
  const float* b_ih      = (const float*)d_in[9];
  const float* b_hh      = (const float*)d_in[10];
  const float* W_att_in  = (const float*)d_in[11];
  const float* W_att_out = (const float*)d_in[12];
  const float* W_cls     = (const float*)d_in[13];
  const float* b_cls     = (const float*)d_in[14];
  float* out = (float*)d_out;

  char* ws = (char*)d_ws;
  size_t off = 0;
  auto alloc = [&](size_t bytes) {
    void* p = ws + off;
    off = (off + bytes + 255) & ~(size_t)255;
    return p;
  };
  const size_t NT = (size_t)T_STEPS * N_NODES;      // 160000 rows
  u16*   wgatT = (u16*)alloc((size_t)KC * F_INC * 2);
  u16*   wihb  = (u16*)alloc((size_t)G3 * GHD * 2);
  u16*   whhb  = (u16*)alloc((size_t)G3 * GHD * 2);
  u16*   winb  = (u16*)alloc((size_t)GHD * GHD * 2);
  u16*   woutb = (u16*)alloc((size_t)GHD * 2 * GHD * 2);
  u16*   xw    = (u16*)alloc(NT * KC * 2);          // 164 MB
  float* asrc  = (float*)alloc(NT * 4 * 4);
  float* adst  = (float*)alloc(NT * 4 * 4);
  u16*   yall  = (u16*)alloc(NT * GHD * 2);         // 41 MB
  u16*   giall = (u16*)alloc(NT * G3 * 2);          // 123 MB
  float* ctx   = (float*)alloc(NT * GHD * 4);       // 82 MB
  u16*   hbf   = (u16*)alloc((size_t)N_NODES * GHD * 2);
  float* qf    = (float*)alloc((size_t)N_NODES * GHD * 4);
  u16*   comb  = (u16*)alloc((size_t)N_NODES * 2 * GHD * 2);
  u16*   aob   = (u16*)alloc((size_t)N_NODES * GHD * 2);
  int* counts  = (int*)alloc((size_t)2 * T_STEPS * N_NODES * 4); // counts + cursor
  int* cursor  = counts + T_STEPS * N_NODES;
  int* offs    = (int*)alloc((size_t)T_STEPS * (N_NODES + 1) * 4);
  int* ssrc    = (int*)alloc((size_t)T_STEPS * SEG * 4);

  // weight converts
  conv_transpose_wgat<<<dim3((KC * F_INC + 255) / 256), 256, 0, stream>>>(W_gat, wgatT);
  convert_f32_bf16<<<dim3((G3 * GHD / 4 + 255) / 256), 256, 0, stream>>>(W_ih, wihb, G3 * GHD);
  convert_f32_bf16<<<dim3((G3 * GHD / 4 + 255) / 256), 256, 0, stream>>>(W_hh, whhb, G3 * GHD);
  convert_f32_bf16<<<dim3((GHD * GHD / 4 + 255) / 256), 256, 0, stream>>>(W_att_in, winb, GHD * GHD);
  convert_f32_bf16<<<dim3((GHD * 2 * GHD / 4 + 255) / 256), 256, 0, stream>>>(W_att_out, woutb, GHD * 2 * GHD);

  // batched edge sort
  hipMemsetAsync(counts, 0, (size_t)2 * T_STEPS * N_NODES * 4, stream);
  count_kernel<<<dim3(N_EDGES / 256, T_STEPS), 256, 0, stream>>>(graph, counts);
  scan_kernel<<<dim3(T_STEPS), 1024, 0, stream>>>(counts, offs);
  scatter_kernel<<<dim3((SEG + 255) / 256, T_STEPS), 256, 0, stream>>>(graph, offs, cursor, ssrc);

  // xw = fts @ W_gat for ALL t (fp32 A converted in staging) + fused a_src/a_dst
  gemm_bf16<1, 1, float><<<dim3(KC / 128, NT / 128), 256, 0, stream>>>(
      fts, wgatT, nullptr, xw, (int)NT, F_INC, KC, att_src, att_dst, asrc, adst);

  // batched aggregate -> y for ALL t
  aggregate_kernel<<<dim3(N_NODES / 4, T_STEPS), 256, 0, stream>>>(
      xw, asrc, adst, b_gat, offs, ssrc, yall);

  // gi = y @ W_ih^T + b_ih for ALL t
  gemm_bf16<1, 0, u16><<<dim3(G3 / 128, NT / 128), 256, 0, stream>>>(
      yall, wihb, b_ih, giall, (int)NT, GHD, G3, nullptr, nullptr, nullptr, nullptr);

  // GRU recurrence
  gru_combine0<<<dim3(N_NODES * GHD / 256), 256, 0, stream>>>(giall, b_hh, ctx, hbf);
  for (int t = 1; t < T_STEPS; ++t) {
    gru_fused<<<dim3((N_NODES + 63) / 64), 256, 0, stream>>>(
        hbf, whhb, b_hh, giall + (size_t)t * N_NODES * G3,
        ctx + (size_t)(t - 1) * N_NODES * GHD,
        ctx + (size_t)t * N_NODES * GHD, hbf);
  }

  // temporal attention tail
  gemm_bf16<0, 0, u16><<<dim3(1, (N_NODES + 127) / 128), 256, 0, stream>>>(
      hbf, winb, nullptr, qf, N_NODES, GHD, GHD, nullptr, nullptr, nullptr, nullptr);
  attn_mid<<<dim3(N_NODES / 4), 256, 0, stream>>>(ctx, qf, comb);
  gemm_bf16<1, 0, u16><<<dim3(1, (N_NODES + 127) / 128), 256, 0, stream>>>(
      comb, woutb, nullptr, aob, N_NODES, 2 * GHD, GHD, nullptr, nullptr, nullptr, nullptr);
  logits_kernel<<<dim3(N_NODES / 4), 256, 0, stream>>>(aob, W_cls, b_cls, out);
}

// Round 4
// 838.856 us; speedup vs baseline: 3.8302x; 1.0626x over previous
//
#include <hip/hip_runtime.h>
#include <hip/hip_bf16.h>
#include <math.h>

#define N_NODES 20000
#define N_EDGES 160000
#define T_STEPS 8
#define F_INC   256
#define HEADS   4
#define CCH     128
#define KC      512   // HEADS*CCH
#define GHD     128
#define G3      384
#define SLOPE   0.2f
#define SEG     (N_EDGES + N_NODES)   // edges + self loops per t

typedef unsigned short u16;
typedef __attribute__((ext_vector_type(8))) short bf16x8;
typedef __attribute__((ext_vector_type(4))) float f32x4;

__device__ __forceinline__ float leakyf(float x) { return x > 0.f ? x : SLOPE * x; }
__device__ __forceinline__ float b2f(u16 u) {
  union { unsigned int i; float f; } x; x.i = ((unsigned int)u) << 16; return x.f;
}
__device__ __forceinline__ u16 f2b(float f) {
  union { float f; unsigned int i; } u; u.f = f;
  unsigned int r = u.i + 0x7FFFu + ((u.i >> 16) & 1u);
  return (u16)(r >> 16);
}
__device__ __forceinline__ float sigf(float x) { return 1.f / (1.f + expf(-x)); }

// async global->LDS 16B (wave-uniform LDS base + lane*16; per-lane global src)
__device__ __forceinline__ void gload16(const void* g, void* l) {
  __builtin_amdgcn_global_load_lds(
      (const __attribute__((address_space(1))) unsigned int*)g,
      (__attribute__((address_space(3))) unsigned int*)l, 16, 0, 0);
}

// ---------------------------------------------------------------------------
// bf16 MFMA GEMM: C[M,Nt] = A[M,K] @ B^T (+bias). A (M,K) bf16, B (Nt,K) bf16.
// 256 thr / 4 waves, tile 128x128, BK=32, 16x16x32 MFMA, fp32 accum.
// global_load_lds staging with XOR slot-swizzle folded into the per-lane
// GLOBAL source address (LDS dest linear). swz=1: bijective XCD-chunked
// block swizzle (consecutive linear blocks -> same XCD L2).
// FUSE=1 (xw gemm): fused a_src/a_dst row-dots (each 128-col tile = 1 head).
// ---------------------------------------------------------------------------
template <int OBF, int FUSE>
__global__ __launch_bounds__(256) void gemm_bf16(
    const u16* __restrict__ A, const u16* __restrict__ B,
    const float* __restrict__ bias, void* __restrict__ Cout,
    int M, int K, int Nt, int swz,
    const float* __restrict__ attS, const float* __restrict__ attD,
    float* __restrict__ asrc, float* __restrict__ adst)
{
  __shared__ u16 As[128][32];
  __shared__ u16 Bs[128][32];
  __shared__ float s_as[128], s_ad[128];
  const int tid  = threadIdx.x;
  const int wave = tid >> 6, lane = tid & 63;
  const int wr = (wave >> 1) * 64, wc = (wave & 1) * 64;
  int bx = blockIdx.x, by = blockIdx.y;
  if (swz) {
    const int gx = gridDim.x;
    const int nwg = gx * (int)gridDim.y;
    const int lin = by * gx + bx;
    const int q = nwg >> 3, r = nwg & 7;
    const int xcd = lin & 7, idx = lin >> 3;
    const int wg = (xcd < r ? xcd * (q + 1) : r * (q + 1) + (xcd - r) * q) + idx;
    bx = wg % gx; by = wg / gx;
  }
  const int bm = by * 128, bn = bx * 128;
  const int l15 = lane & 15, g = lane >> 4;

  if (FUSE && tid < 128) { s_as[tid] = 0.f; s_ad[tid] = 0.f; }

  // staging: slot idx = tid + p*256 -> LDS row idx>>2, slot idx&3 (linear).
  // source k-slot = dest-slot ^ ((row>>1)&3)  (same for row and row+64)
  const int sr = tid >> 2, sd = tid & 3;
  const int ss = sd ^ ((sr >> 1) & 3);
  const u16* aS0 = A + (size_t)min(bm + sr,      M - 1) * K + ss * 8;
  const u16* aS1 = A + (size_t)min(bm + 64 + sr, M - 1) * K + ss * 8;
  const u16* bS0 = B + (size_t)(bn + sr)      * K + ss * 8;
  const u16* bS1 = B + (size_t)(bn + 64 + sr) * K + ss * 8;
  u16* lA0 = &As[0][0] + (size_t)(tid & ~63) * 8;
  u16* lA1 = lA0 + 2048;
  u16* lB0 = &Bs[0][0] + (size_t)(tid & ~63) * 8;
  u16* lB1 = lB0 + 2048;

  f32x4 acc[4][4];
  #pragma unroll
  for (int m = 0; m < 4; ++m)
    #pragma unroll
    for (int n = 0; n < 4; ++n)
      #pragma unroll
      for (int j = 0; j < 4; ++j) acc[m][n][j] = 0.f;

  const int nK = K >> 5;
  for (int kt = 0; kt < nK; ++kt) {
    const int ko = kt * 32;
    gload16(aS0 + ko, lA0);
    gload16(aS1 + ko, lA1);
    gload16(bS0 + ko, lB0);
    gload16(bS1 + ko, lB1);
    __syncthreads();
    bf16x8 af[4], bfr[4];
    #pragma unroll
    for (int m = 0; m < 4; ++m) {
      int row = wr + m * 16 + l15;
      af[m] = *(const bf16x8*)&As[row][(g ^ ((row >> 1) & 3)) * 8];
      int rowb = wc + m * 16 + l15;
      bfr[m] = *(const bf16x8*)&Bs[rowb][(g ^ ((rowb >> 1) & 3)) * 8];
    }
    #pragma unroll
    for (int m = 0; m < 4; ++m)
      #pragma unroll
      for (int n = 0; n < 4; ++n)
        acc[m][n] = __builtin_amdgcn_mfma_f32_16x16x32_bf16(af[m], bfr[n], acc[m][n], 0, 0, 0);
    __syncthreads();
  }
  // epilogue: C/D layout col=lane&15, row=(lane>>4)*4+reg
  #pragma unroll
  for (int m = 0; m < 4; ++m) {
    int row0 = bm + wr + m * 16 + g * 4;
    #pragma unroll
    for (int n = 0; n < 4; ++n) {
      int col = bn + wc + n * 16 + l15;
      float bv = bias ? bias[col] : 0.f;
      #pragma unroll
      for (int j = 0; j < 4; ++j) {
        int row = row0 + j;
        if (row < M) {
          float v = acc[m][n][j] + bv;
          if (OBF) ((u16*)Cout)[(size_t)row * Nt + col] = f2b(v);
          else     ((float*)Cout)[(size_t)row * Nt + col] = v;
        }
      }
    }
  }
  if (FUSE) {
    float ps[4][4], pd[4][4];
    #pragma unroll
    for (int m = 0; m < 4; ++m)
      #pragma unroll
      for (int j = 0; j < 4; ++j) { ps[m][j] = 0.f; pd[m][j] = 0.f; }
    #pragma unroll
    for (int n = 0; n < 4; ++n) {
      int cl = wc + n * 16 + l15;
      float wsv = attS[bn + cl], wdv = attD[bn + cl];
      #pragma unroll
      for (int m = 0; m < 4; ++m)
        #pragma unroll
        for (int j = 0; j < 4; ++j) {
          ps[m][j] = fmaf(acc[m][n][j], wsv, ps[m][j]);
          pd[m][j] = fmaf(acc[m][n][j], wdv, pd[m][j]);
        }
    }
    #pragma unroll
    for (int m = 0; m < 4; ++m)
      #pragma unroll
      for (int j = 0; j < 4; ++j)
        #pragma unroll
        for (int msk = 8; msk >= 1; msk >>= 1) {
          ps[m][j] += __shfl_xor(ps[m][j], msk);
          pd[m][j] += __shfl_xor(pd[m][j], msk);
        }
    if (l15 == 0) {
      #pragma unroll
      for (int m = 0; m < 4; ++m)
        #pragma unroll
        for (int j = 0; j < 4; ++j) {
          atomicAdd(&s_as[wr + m * 16 + g * 4 + j], ps[m][j]);
          atomicAdd(&s_ad[wr + m * 16 + g * 4 + j], pd[m][j]);
        }
    }
    __syncthreads();
    if (tid < 128) {
      int row = bm + tid;
      if (row < M) {
        int h = bn >> 7;
        asrc[(size_t)row * 4 + h] = s_as[tid];
        adst[(size_t)row * 4 + h] = s_ad[tid];
      }
    }
  }
}

// ---------------------------------------------------------------------------
// fp32 -> bf16 convert, 8 elems/thread (n % 8 == 0)
// ---------------------------------------------------------------------------
__global__ void convert_f32_bf16(const float* __restrict__ src, u16* __restrict__ dst, int n) {
  int i = (blockIdx.x * 256 + threadIdx.x) * 8;
  if (i >= n) return;
  float4 v0 = *(const float4*)(src + i);
  float4 v1 = *(const float4*)(src + i + 4);
  bf16x8 o;
  o[0] = (short)f2b(v0.x); o[1] = (short)f2b(v0.y);
  o[2] = (short)f2b(v0.z); o[3] = (short)f2b(v0.w);
  o[4] = (short)f2b(v1.x); o[5] = (short)f2b(v1.y);
  o[6] = (short)f2b(v1.z); o[7] = (short)f2b(v1.w);
  *(bf16x8*)(dst + i) = o;
}

__global__ void conv_transpose_wgat(const float* __restrict__ src, u16* __restrict__ dst) {
  int idx = blockIdx.x * 256 + threadIdx.x;
  if (idx >= KC * F_INC) return;
  int n = idx >> 8, k = idx & 255;
  dst[(size_t)n * F_INC + k] = f2b(src[(size_t)k * KC + n]);
}

// ---------------------------------------------------------------------------
// Batched edge counting-sort (all T at once)
// ---------------------------------------------------------------------------
__global__ void count_kernel(const int* __restrict__ graph, int* __restrict__ counts) {
  int e = blockIdx.x * 256 + threadIdx.x;
  int t = blockIdx.y;
  if (e < N_EDGES) {
    int d = graph[(size_t)t * 2 * N_EDGES + N_EDGES + e];
    atomicAdd(&counts[t * N_NODES + d], 1);
  }
}

__global__ __launch_bounds__(1024) void scan_kernel(
    const int* __restrict__ counts, int* __restrict__ offs)
{
  const int t = blockIdx.x;
  const int tid = threadIdx.x, lane = tid & 63, w = tid >> 6;
  __shared__ int s_wt[16];
  int carry = 0;
  const int base_abs = t * SEG;
  for (int base = 0; base < N_NODES; base += 1024) {
    int i = base + tid;
    int v = (i < N_NODES) ? (counts[t * N_NODES + i] + 1) : 0;  // +1 self loop
    int x = v;
    #pragma unroll
    for (int d = 1; d < 64; d <<= 1) {
      int nvl = __shfl_up(x, d, 64);
      if (lane >= d) x += nvl;
    }
    if (lane == 63) s_wt[w] = x;
    __syncthreads();
    if (tid < 16) {
      int y = s_wt[tid];
      #pragma unroll
      for (int d = 1; d < 16; d <<= 1) {
        int nvl = __shfl_up(y, d, 64);
        if (tid >= d) y += nvl;
      }
      s_wt[tid] = y;
    }
    __syncthreads();
    int wbase = (w > 0) ? s_wt[w - 1] : 0;
    int total = s_wt[15];
    if (i < N_NODES) offs[t * (N_NODES + 1) + i] = base_abs + carry + wbase + x - v;
    carry += total;
    __syncthreads();
  }
  if (tid == 0) offs[t * (N_NODES + 1) + N_NODES] = base_abs + carry;
}

__global__ void scatter_kernel(const int* __restrict__ graph, const int* __restrict__ offs,
                               int* __restrict__ cursor, int* __restrict__ ssrc)
{
  int i = blockIdx.x * 256 + threadIdx.x;
  int t = blockIdx.y;
  if (i >= SEG) return;
  int s, d;
  if (i < N_EDGES) {
    s = graph[(size_t)t * 2 * N_EDGES + i];
    d = graph[(size_t)t * 2 * N_EDGES + N_EDGES + i];
  } else {
    s = d = i - N_EDGES;
  }
  int pos = offs[t * (N_NODES + 1) + d] + atomicAdd(&cursor[t * N_NODES + d], 1);
  ssrc[pos] = s;
}

// ---------------------------------------------------------------------------
// Batched aggregate: one wave per (t, node); lane owns 8 contiguous channels
// (all within head lane>>4). 16B coalesced xw row loads, softmax via shfl.
// ---------------------------------------------------------------------------
__global__ __launch_bounds__(256) void aggregate_kernel(
    const u16* __restrict__ xw, const float* __restrict__ a_src,
    const float* __restrict__ a_dst, const float* __restrict__ b_gat,
    const int* __restrict__ offs, const int* __restrict__ ssrc,
    u16* __restrict__ yout)
{
  const int wv = threadIdx.x >> 6, lane = threadIdx.x & 63;
  const int nd = blockIdx.x * 4 + wv;
  const int t  = blockIdx.y;
  __shared__ float s_w[4][64][4];
  __shared__ int   s_s[4][64];
  const int ob = t * (N_NODES + 1) + nd;
  const int beg = offs[ob], end = offs[ob + 1];
  const size_t rowbase = (size_t)t * N_NODES;
  const float4 adv = *(const float4*)&a_dst[(rowbase + nd) * 4];
  const int hl = lane >> 4;

  float m0=-INFINITY, m1=-INFINITY, m2=-INFINITY, m3=-INFINITY;
  float s0=0.f, s1=0.f, s2=0.f, s3=0.f;
  for (int base = beg; base < end; base += 64) {
    int e = base + lane;
    float a0=-INFINITY, a1=-INFINITY, a2=-INFINITY, a3=-INFINITY;
    if (e < end) {
      int s = ssrc[e];
      float4 av = *(const float4*)&a_src[(rowbase + s) * 4];
      a0 = leakyf(av.x + adv.x); a1 = leakyf(av.y + adv.y);
      a2 = leakyf(av.z + adv.z); a3 = leakyf(av.w + adv.w);
    }
    float c0=a0, c1=a1, c2=a2, c3=a3;
    #pragma unroll
    for (int msk = 32; msk >= 1; msk >>= 1) {
      c0 = fmaxf(c0, __shfl_xor(c0, msk)); c1 = fmaxf(c1, __shfl_xor(c1, msk));
      c2 = fmaxf(c2, __shfl_xor(c2, msk)); c3 = fmaxf(c3, __shfl_xor(c3, msk));
    }
    float n0 = fmaxf(m0, c0), n1 = fmaxf(m1, c1), n2 = fmaxf(m2, c2), n3 = fmaxf(m3, c3);
    float e0 = expf(a0 - n0), e1 = expf(a1 - n1), e2 = expf(a2 - n2), e3 = expf(a3 - n3);
    #pragma unroll
    for (int msk = 32; msk >= 1; msk >>= 1) {
      e0 += __shfl_xor(e0, msk); e1 += __shfl_xor(e1, msk);
      e2 += __shfl_xor(e2, msk); e3 += __shfl_xor(e3, msk);
    }
    s0 = s0 * expf(m0 - n0) + e0; s1 = s1 * expf(m1 - n1) + e1;
    s2 = s2 * expf(m2 - n2) + e2; s3 = s3 * expf(m3 - n3) + e3;
    m0 = n0; m1 = n1; m2 = n2; m3 = n3;
  }
  const float i0 = 1.f/(s0+1e-16f), i1 = 1.f/(s1+1e-16f);
  const float i2 = 1.f/(s2+1e-16f), i3 = 1.f/(s3+1e-16f);

  float acc[8] = {0.f,0.f,0.f,0.f,0.f,0.f,0.f,0.f};
  for (int base = beg; base < end; base += 64) {
    int e = base + lane;
    if (e < end) {
      int s = ssrc[e];
      float4 av = *(const float4*)&a_src[(rowbase + s) * 4];
      s_s[wv][lane] = s;
      s_w[wv][lane][0] = expf(leakyf(av.x + adv.x) - m0) * i0;
      s_w[wv][lane][1] = expf(leakyf(av.y + adv.y) - m1) * i1;
      s_w[wv][lane][2] = expf(leakyf(av.z + adv.z) - m2) * i2;
      s_w[wv][lane][3] = expf(leakyf(av.w + adv.w) - m3) * i3;
    }
    int cnt = min(64, end - base);
    for (int e2 = 0; e2 < cnt; ++e2) {
      float w = s_w[wv][e2][hl];
      const int4 xi = *(const int4*)&xw[(rowbase + s_s[wv][e2]) * KC + lane * 8];
      acc[0] = fmaf(w, b2f((u16)(xi.x & 0xffff)), acc[0]);
      acc[1] = fmaf(w, b2f((u16)((unsigned)xi.x >> 16)), acc[1]);
      acc[2] = fmaf(w, b2f((u16)(xi.y & 0xffff)), acc[2]);
      acc[3] = fmaf(w, b2f((u16)((unsigned)xi.y >> 16)), acc[3]);
      acc[4] = fmaf(w, b2f((u16)(xi.z & 0xffff)), acc[4]);
      acc[5] = fmaf(w, b2f((u16)((unsigned)xi.z >> 16)), acc[5]);
      acc[6] = fmaf(w, b2f((u16)(xi.w & 0xffff)), acc[6]);
      acc[7] = fmaf(w, b2f((u16)((unsigned)xi.w >> 16)), acc[7]);
    }
  }
  #pragma unroll
  for (int k = 0; k < 8; ++k) {
    acc[k] += __shfl_xor(acc[k], 16);
    acc[k] += __shfl_xor(acc[k], 32);
  }
  if (lane < 16) {
    bf16x8 ov;
    #pragma unroll
    for (int k = 0; k < 8; ++k) {
      float v = acc[k] * 0.25f + b_gat[lane * 8 + k];
      ov[k] = (short)f2b(leakyf(v));
    }
    *(bf16x8*)&yout[(rowbase + nd) * GHD + lane * 8] = ov;
  }
}

// ---------------------------------------------------------------------------
// GRU t=0 combine (h_prev = 0, gh = b_hh); writes ctx0 bf16 + hf fp32
// ---------------------------------------------------------------------------
__global__ void gru_combine0(const u16* __restrict__ gi_t, const float* __restrict__ b_hh,
                             u16* __restrict__ ctx0, float* __restrict__ hf)
{
  int idx = blockIdx.x * 256 + threadIdx.x;
  if (idx >= N_NODES * GHD) return;
  int n = idx >> 7, c = idx & 127;
  size_t gb = (size_t)n * G3;
  float ir = b2f(gi_t[gb + c]), iz = b2f(gi_t[gb + 128 + c]), in_ = b2f(gi_t[gb + 256 + c]);
  float r = sigf(ir + b_hh[c]);
  float z = sigf(iz + b_hh[128 + c]);
  float nn = tanhf(in_ + r * b_hh[256 + c]);
  float h = (1.f - z) * nn;
  ctx0[idx] = f2b(h);
  hf[idx] = h;
}

// ---------------------------------------------------------------------------
// Fused gh-GEMM (64x384 tile) + GRU combine. A = ctx[t-1] (bf16), carry hf
// fp32 in-place; writes ctx[t] bf16 + hf. global_load_lds staging.
// ---------------------------------------------------------------------------
__global__ __launch_bounds__(256) void gru_fused(
    const u16* __restrict__ hprev, const u16* __restrict__ Whh,
    const float* __restrict__ b_hh, const u16* __restrict__ gi_t,
    float* __restrict__ hf, u16* __restrict__ ctx_out)
{
  __shared__ u16 lds[64 * 384];                       // 48 KB, dual-purpose
  u16 (*As)[32] = (u16(*)[32])lds;                    // 64 x 32
  u16 (*Bs)[32] = (u16(*)[32])(lds + 64 * 32);        // 384 x 32
  const int tid = threadIdx.x, lane = tid & 63, wv = tid >> 6;
  const int l15 = lane & 15, g = lane >> 4;
  const int bm = blockIdx.x * 64;

  const int sr = tid >> 2, sd = tid & 3;
  const int ss = sd ^ ((sr >> 1) & 3);
  const u16* aS = hprev + (size_t)min(bm + sr, N_NODES - 1) * GHD + ss * 8;
  u16* lA = lds + (size_t)tid * 8 - (size_t)(lane & 63) * 8 + (size_t)(lane) * 8; // = lds + tid*8
  lA = lds + (size_t)(tid & ~63) * 8;
  const u16* bS[6]; u16* lB[6];
  #pragma unroll
  for (int p = 0; p < 6; ++p) {
    int r = sr + p * 64;
    bS[p] = Whh + (size_t)r * GHD + ss * 8;           // (r>>1)&3 invariant mod 64-row shift
    lB[p] = lds + 64 * 32 + (size_t)(p * 256 + (tid & ~63)) * 8;
  }

  f32x4 acc[4][6];
  #pragma unroll
  for (int m = 0; m < 4; ++m)
    #pragma unroll
    for (int n = 0; n < 6; ++n)
      #pragma unroll
      for (int j = 0; j < 4; ++j) acc[m][n][j] = 0.f;

  #pragma unroll
  for (int kt = 0; kt < 4; ++kt) {
    const int ko = kt * 32;
    gload16(aS + ko, lA);
    #pragma unroll
    for (int p = 0; p < 6; ++p) gload16(bS[p] + ko, lB[p]);
    __syncthreads();
    bf16x8 af[4], bfr[6];
    #pragma unroll
    for (int m = 0; m < 4; ++m) {
      int row = m * 16 + l15;
      af[m] = *(const bf16x8*)&As[row][(g ^ ((row >> 1) & 3)) * 8];
    }
    #pragma unroll
    for (int n = 0; n < 6; ++n) {
      int row = wv * 96 + n * 16 + l15;
      bfr[n] = *(const bf16x8*)&Bs[row][(g ^ ((row >> 1) & 3)) * 8];
    }
    #pragma unroll
    for (int m = 0; m < 4; ++m)
      #pragma unroll
      for (int n = 0; n < 6; ++n)
        acc[m][n] = __builtin_amdgcn_mfma_f32_16x16x32_bf16(af[m], bfr[n], acc[m][n], 0, 0, 0);
    __syncthreads();
  }
  // gh (+b_hh) -> LDS bf16, swizzled: slot' = (c>>3) ^ (r&7)
  #pragma unroll
  for (int m = 0; m < 4; ++m)
    #pragma unroll
    for (int n = 0; n < 6; ++n) {
      int c = wv * 96 + n * 16 + l15;
      float bb = b_hh[c];
      #pragma unroll
      for (int j = 0; j < 4; ++j) {
        int r = m * 16 + g * 4 + j;
        lds[r * 384 + (((c >> 3) ^ (r & 7)) << 3) + (c & 7)] = f2b(acc[m][n][j] + bb);
      }
    }
  __syncthreads();
  {
    int r = tid >> 2, gr = bm + r;
    if (gr < N_NODES) {
      const int cg = (tid & 3) * 32;
      const size_t gb = (size_t)gr * G3;
      const size_t cb = (size_t)gr * GHD;
      #pragma unroll
      for (int q = 0; q < 4; ++q) {
        int c0 = cg + q * 8;
        int sl0 = ((c0 >> 3) ^ (r & 7));
        int sl1 = (((128 + c0) >> 3) ^ (r & 7));
        int sl2 = (((256 + c0) >> 3) ^ (r & 7));
        bf16x8 hr8 = *(bf16x8*)&lds[r * 384 + sl0 * 8];
        bf16x8 hz8 = *(bf16x8*)&lds[r * 384 + sl1 * 8];
        bf16x8 hn8 = *(bf16x8*)&lds[r * 384 + sl2 * 8];
        bf16x8 ir8 = *(const bf16x8*)&gi_t[gb + c0];
        bf16x8 iz8 = *(const bf16x8*)&gi_t[gb + 128 + c0];
        bf16x8 in8 = *(const bf16x8*)&gi_t[gb + 256 + c0];
        float4 hp0 = *(const float4*)&hf[cb + c0];
        float4 hp1 = *(const float4*)&hf[cb + c0 + 4];
        float hp[8] = {hp0.x, hp0.y, hp0.z, hp0.w, hp1.x, hp1.y, hp1.z, hp1.w};
        float cv[8];
        bf16x8 hv;
        #pragma unroll
        for (int k = 0; k < 8; ++k) {
          float rr = sigf(b2f((u16)ir8[k]) + b2f((u16)hr8[k]));
          float zz = sigf(b2f((u16)iz8[k]) + b2f((u16)hz8[k]));
          float nn = tanhf(b2f((u16)in8[k]) + rr * b2f((u16)hn8[k]));
          float h = (1.f - zz) * nn + zz * hp[k];
          cv[k] = h;
          hv[k] = (short)f2b(h);
        }
        *(float4*)&hf[cb + c0]     = make_float4(cv[0], cv[1], cv[2], cv[3]);
        *(float4*)&hf[cb + c0 + 4] = make_float4(cv[4], cv[5], cv[6], cv[7]);
        *(bf16x8*)&ctx_out[cb + c0] = hv;
      }
    }
  }
}

// ---------------------------------------------------------------------------
// Temporal attention middle: scores + softmax + mix. One wave / node.
// ctx is bf16 now.
// ---------------------------------------------------------------------------
__global__ __launch_bounds__(256) void attn_mid(
    const u16* __restrict__ ctx, const float* __restrict__ q,
    u16* __restrict__ comb)
{
  const int node = blockIdx.x * 4 + (threadIdx.x >> 6);
  const int lane = threadIdx.x & 63;
  if (node >= N_NODES) return;
  const float q0 = q[(size_t)node * GHD + lane];
  const float q1 = q[(size_t)node * GHD + 64 + lane];
  float c0[T_STEPS], c1[T_STEPS], w[T_STEPS];
  float mx = -1e30f;
  #pragma unroll
  for (int t = 0; t < T_STEPS; ++t) {
    const u16* cr = ctx + ((size_t)t * N_NODES + node) * GHD;
    c0[t] = b2f(cr[lane]); c1[t] = b2f(cr[64 + lane]);
    float p = q0 * c0[t] + q1 * c1[t];
    #pragma unroll
    for (int m = 32; m >= 1; m >>= 1) p += __shfl_xor(p, m);
    w[t] = p;
    mx = fmaxf(mx, p);
  }
  float s = 0.f;
  #pragma unroll
  for (int t = 0; t < T_STEPS; ++t) { w[t] = expf(w[t] - mx); s += w[t]; }
  const float inv = 1.f / s;
  float m0 = 0.f, m1 = 0.f;
  #pragma unroll
  for (int t = 0; t < T_STEPS; ++t) { m0 = fmaf(w[t], c0[t], m0); m1 = fmaf(w[t], c1[t], m1); }
  m0 *= inv; m1 *= inv;
  u16* cb = comb + (size_t)node * 2 * GHD;
  cb[lane]       = f2b(m0);
  cb[64 + lane]  = f2b(m1);
  cb[128 + lane] = f2b(q0);
  cb[192 + lane] = f2b(q1);
}

// ---------------------------------------------------------------------------
// tanh + leaky + classifier + log_softmax. One wave / node.
// ---------------------------------------------------------------------------
__global__ __launch_bounds__(256) void logits_kernel(
    const u16* __restrict__ ao, const float* __restrict__ W_cls,
    const float* __restrict__ b_cls, float* __restrict__ out)
{
  const int node = blockIdx.x * 4 + (threadIdx.x >> 6);
  const int lane = threadIdx.x & 63;
  if (node >= N_NODES) return;
  float o0 = leakyf(tanhf(b2f(ao[(size_t)node * GHD + lane])));
  float o1 = leakyf(tanhf(b2f(ao[(size_t)node * GHD + 64 + lane])));
  float p0 = o0 * W_cls[lane] + o1 * W_cls[64 + lane];
  float p1 = o0 * W_cls[128 + lane] + o1 * W_cls[192 + lane];
  #pragma unroll
  for (int m = 32; m >= 1; m >>= 1) { p0 += __shfl_xor(p0, m); p1 += __shfl_xor(p1, m); }
  if (lane == 0) {
    float l0 = p0 + b_cls[0];
    float l1 = p1 + b_cls[1];
    float mx = fmaxf(l0, l1);
    float lse = mx + logf(expf(l0 - mx) + expf(l1 - mx));
    out[(size_t)node * 2 + 0] = l0 - lse;
    out[(size_t)node * 2 + 1] = l1 - lse;
  }
}

// ---------------------------------------------------------------------------
extern "C" void kernel_launch(void* const* d_in, const int* in_sizes, int n_in,
                              void* d_out, int out_size, void* d_ws, size_t ws_size,
                              hipStream_t stream)
{
  const int*   graph     = (const int*)  d_in[0];
  const float* fts       = (const float*)d_in[1];
  const float* W_gat     = (const float*)d_in[3];
  const float* att_src   = (const float*)d_in[4];
  const float* att_dst   = (const float*)d_in[5];
  const float* b_gat     = (const float*)d_in[6];
  const float* W_ih      = (const float*)d_in[7];
  const float* W_hh      = (const float*)d_in[8];
  const float* b_ih      = (const float*)d_in[9];
  const float* b_hh      = (const float*)d_in[10];
  const float* W_att_in  = (const float*)d_in[11];
  const float* W_att_out = (const float*)d_in[12];
  const float* W_cls     = (const float*)d_in[13];
  const float* b_cls     = (const float*)d_in[14];
  float* out = (float*)d_out;

  char* ws = (char*)d_ws;
  size_t off = 0;
  auto alloc = [&](size_t bytes) {
    void* p = ws + off;
    off = (off + bytes + 255) & ~(size_t)255;
    return p;
  };
  const size_t NT = (size_t)T_STEPS * N_NODES;      // 160000 rows
  u16*   wgatT = (u16*)alloc((size_t)KC * F_INC * 2);
  u16*   wihb  = (u16*)alloc((size_t)G3 * GHD * 2);
  u16*   whhb  = (u16*)alloc((size_t)G3 * GHD * 2);
  u16*   winb  = (u16*)alloc((size_t)GHD * GHD * 2);
  u16*   woutb = (u16*)alloc((size_t)GHD * 2 * GHD * 2);
  u16*   fbf   = (u16*)alloc(NT * F_INC * 2);       // 82 MB  fts bf16
  u16*   xw    = (u16*)alloc(NT * KC * 2);          // 164 MB
  float* asrc  = (float*)alloc(NT * 4 * 4);
  float* adst  = (float*)alloc(NT * 4 * 4);
  u16*   yall  = (u16*)alloc(NT * GHD * 2);         // 41 MB
  u16*   giall = (u16*)alloc(NT * G3 * 2);          // 123 MB
  u16*   ctx   = (u16*)alloc(NT * GHD * 2);         // 41 MB (bf16 h record)
  float* hf    = (float*)alloc((size_t)N_NODES * GHD * 4); // fp32 h carry
  float* qf    = (float*)alloc((size_t)N_NODES * GHD * 4);
  u16*   comb  = (u16*)alloc((size_t)N_NODES * 2 * GHD * 2);
  u16*   aob   = (u16*)alloc((size_t)N_NODES * GHD * 2);
  int* counts  = (int*)alloc((size_t)2 * T_STEPS * N_NODES * 4); // counts + cursor
  int* cursor  = counts + T_STEPS * N_NODES;
  int* offs    = (int*)alloc((size_t)T_STEPS * (N_NODES + 1) * 4);
  int* ssrc    = (int*)alloc((size_t)T_STEPS * SEG * 4);

  // weight converts
  conv_transpose_wgat<<<dim3((KC * F_INC + 255) / 256), 256, 0, stream>>>(W_gat, wgatT);
  convert_f32_bf16<<<dim3(G3 * GHD / 8 / 256), 256, 0, stream>>>(W_ih, wihb, G3 * GHD);
  convert_f32_bf16<<<dim3(G3 * GHD / 8 / 256), 256, 0, stream>>>(W_hh, whhb, G3 * GHD);
  convert_f32_bf16<<<dim3(GHD * GHD / 8 / 256), 256, 0, stream>>>(W_att_in, winb, GHD * GHD);
  convert_f32_bf16<<<dim3(GHD * 2 * GHD / 8 / 256), 256, 0, stream>>>(W_att_out, woutb, GHD * 2 * GHD);

  // batched edge sort
  hipMemsetAsync(counts, 0, (size_t)2 * T_STEPS * N_NODES * 4, stream);
  count_kernel<<<dim3(N_EDGES / 256, T_STEPS), 256, 0, stream>>>(graph, counts);
  scan_kernel<<<dim3(T_STEPS), 1024, 0, stream>>>(counts, offs);
  scatter_kernel<<<dim3((SEG + 255) / 256, T_STEPS), 256, 0, stream>>>(graph, offs, cursor, ssrc);

  // fts -> bf16 (one streaming pass)
  convert_f32_bf16<<<dim3((int)(NT * F_INC / 8 / 256)), 256, 0, stream>>>(
      fts, fbf, (int)(NT * F_INC));

  // xw = fbf @ W_gat^T for ALL t + fused a_src/a_dst
  gemm_bf16<1, 1><<<dim3(KC / 128, (int)(NT / 128)), 256, 0, stream>>>(
      fbf, wgatT, nullptr, xw, (int)NT, F_INC, KC, 1, att_src, att_dst, asrc, adst);

  // batched aggregate -> y for ALL t
  aggregate_kernel<<<dim3(N_NODES / 4, T_STEPS), 256, 0, stream>>>(
      xw, asrc, adst, b_gat, offs, ssrc, yall);

  // gi = y @ W_ih^T + b_ih for ALL t
  gemm_bf16<1, 0><<<dim3(G3 / 128, (int)(NT / 128)), 256, 0, stream>>>(
      yall, wihb, b_ih, giall, (int)NT, GHD, G3, 1, nullptr, nullptr, nullptr, nullptr);

  // GRU recurrence (ctx record bf16, carry fp32 in hf)
  gru_combine0<<<dim3(N_NODES * GHD / 256), 256, 0, stream>>>(giall, b_hh, ctx, hf);
  for (int t = 1; t < T_STEPS; ++t) {
    gru_fused<<<dim3((N_NODES + 63) / 64), 256, 0, stream>>>(
        ctx + (size_t)(t - 1) * N_NODES * GHD, whhb, b_hh,
        giall + (size_t)t * N_NODES * G3, hf,
        ctx + (size_t)t * N_NODES * GHD);
  }

  // temporal attention tail
  gemm_bf16<0, 0><<<dim3(1, (N_NODES + 127) / 128), 256, 0, stream>>>(
      ctx + (size_t)(T_STEPS - 1) * N_NODES * GHD, winb, nullptr, qf,
      N_NODES, GHD, GHD, 0, nullptr, nullptr, nullptr, nullptr);
  attn_mid<<<dim3(N_NODES / 4), 256, 0, stream>>>(ctx, qf, comb);
  gemm_bf16<1, 0><<<dim3(1, (N_NODES + 127) / 128), 256, 0, stream>>>(
      comb, woutb, nullptr, aob, N_NODES, 2 * GHD, GHD, 0, nullptr, nullptr, nullptr, nullptr);
  logits_kernel<<<dim3(N_NODES / 4), 256, 0, stream>>>(aob, W_cls, b_cls, out);
}